// Round 8
// baseline (271.758 us; speedup 1.0000x reference)
//
#include <hip/hip_runtime.h>
#include <math.h>

// ---------------------------------------------------------------------------
// GAT_23613730193923 — round 17: 4 blocks/CU. Grid = exactly 4 blocks/CU of
// work, so 3-residency (rounds 14-16) was useless (3+1 rounds == 2+2).
// 4-residency = single round. Requires LDS <= 40960B and VGPR <= 64:
//  - single ping-pong buffer b2 (T1/P/Q/x1/Zp), +2 barriers, b1 deleted.
//  - xc cols 56-63 are exact zeros: MFMA reads replaced by constant-zero
//    frags for (quad==3,kb8==4) lanes (bitwise identical); freed bytes host
//    spH2/sfS/yhsS.
//  - zf dedicated 4KB; alS + late scratch alias dead b2.
//  - MLP in 3 chunks (32/32/16) so mHd fits b2 (16KB).
//  - __launch_bounds__(512,8): VGPR cap 64 (natural in r14-16).
// LDS = 40960B exactly. All math order-identical to round 16.
// ---------------------------------------------------------------------------

#define NEGBIG (-1e30f)

// ---- workspace offsets (floats) ----
#define OFF_A     7471104    // 80*80
#define OFF_AN22  7481600    // 16*16
#define OFF_MK    7484356    // 16*64
#define OFF_GAH   7514692    // W1a hi: 64*64 ushort
#define OFF_GAL   7516740
#define OFF_G2AT  7521156    // 51*64 fp32
#define OFF_SC    7524420    // 1
#define OFF_W1H   7524424    // 128*64 ushort
#define OFF_W1L   7528520
#define OFF_W2H   7532616    // 128*128 ushort
#define OFF_W2L   7540808
#define OFF_W3H   7549000    // 64*128 ushort
#define OFF_W3L   7553096
#define OFF_ANH   7557192    // An11 hi: 64*64 ushort
#define OFF_ANL   7559240
#define OFF_GBH   7561288    // W1b hi: 64*64 ushort
#define OFF_GBL   7563336
#define OFF_WKH   7565384    // Wk^T hi: [h=64][o=64] ushort
#define OFF_WKL   7567432

// ---- output offsets (floats): (out B*16, dist B*6400, A 6400) ----
#define OUT_OUT   0
#define OUT_DIST  16384
#define OUT_A     6569984

typedef __attribute__((ext_vector_type(8))) short bf16x8;
typedef __attribute__((ext_vector_type(4))) short s16x4;
typedef __attribute__((ext_vector_type(4))) float f32x4;

__device__ __forceinline__ unsigned short f2bf(float x) {  // RTN
  union { float f; unsigned u; } v; v.f = x;
  unsigned r = v.u + 0x7fffu + ((v.u >> 16) & 1u);
  return (unsigned short)(r >> 16);
}
__device__ __forceinline__ float bf2f(unsigned short h) {
  union { unsigned u; float f; } v; v.u = ((unsigned)h) << 16; return v.f;
}
__device__ __forceinline__ void split2(float v, unsigned short& h, unsigned short& l) {
  unsigned short hh = f2bf(v);
  h = hh;
  l = f2bf(v - bf2f(hh));
}
__device__ __forceinline__ void split8(const float* v, bf16x8& h8, bf16x8& l8) {
#pragma unroll
  for (int j = 0; j < 8; ++j) {
    unsigned short hh, ll; split2(v[j], hh, ll);
    h8[j] = (short)hh; l8[j] = (short)ll;
  }
}
#define SWZ6(r, k) (((r) << 6) + (((((k) >> 3) ^ ((r) & 7)) << 3) | ((k) & 7)))
#define SWZ7(r, k) (((r) << 7) + (((((k) >> 3) ^ ((r) & 7)) << 3) | ((k) & 7)))

#define MFMA3(acc, aH, aL, bH, bL) \
  acc = __builtin_amdgcn_mfma_f32_16x16x32_bf16(aH, bH, acc, 0, 0, 0); \
  acc = __builtin_amdgcn_mfma_f32_16x16x32_bf16(aH, bL, acc, 0, 0, 0); \
  acc = __builtin_amdgcn_mfma_f32_16x16x32_bf16(aL, bH, acc, 0, 0, 0);
#define MFMA4(acc, aH, aL, bH, bL) \
  MFMA3(acc, aH, aL, bH, bL) \
  acc = __builtin_amdgcn_mfma_f32_16x16x32_bf16(aL, bL, acc, 0, 0, 0);

// ===========================================================================
// k_prep (unchanged)
// ===========================================================================
__global__ __launch_bounds__(256) void k_prep(
    const float* __restrict__ M, const float* __restrict__ Wk,
    const float* __restrict__ sm,
    const float* __restrict__ w1, const float* __restrict__ w2,
    const float* __restrict__ w3,
    const float* __restrict__ wg1a, const float* __restrict__ wg1b,
    const float* __restrict__ wg2a,
    float* __restrict__ ws, float* __restrict__ out)
{
  __shared__ float Msh[80 * 26];
  __shared__ float Ash[80 * 80];
  __shared__ float d1[64];
  __shared__ float d2s[16];
  const int t = threadIdx.x;

  if (blockIdx.x == 0) {
    for (int e = t; e < 80 * 26; e += 256) Msh[e] = M[e];
    __syncthreads();
    for (int e = t; e < 6400; e += 256) {
      int i = e / 80, j = e % 80;
      float v = 0.f;
      if (j < i) {
        float s = 0.f;
        for (int k = 0; k < 26; ++k) s += Msh[i * 26 + k] * Msh[j * 26 + k];
        v = s > 0.f ? s : 0.f;
      }
      Ash[e] = v;
    }
    __syncthreads();
    if (t > 0 && t < 80) {
      int i = t;
      float m = -3.4e38f;
      for (int j = 0; j < i; ++j) m = fmaxf(m, Ash[i * 80 + j]);
      float s = 0.f;
      for (int j = 0; j < i; ++j) {
        float e = expf(Ash[i * 80 + j] - m);
        Ash[i * 80 + j] = e;
        s += e;
      }
      float inv = 1.f / s;
      for (int j = 0; j < i; ++j) Ash[i * 80 + j] *= inv;
    }
    __syncthreads();
    {
      float* Aws = ws + OFF_A;
      float* Aout = out + OUT_A;
      for (int e = t; e < 6400; e += 256) { Aws[e] = Ash[e]; Aout[e] = Ash[e]; }
    }
    if (t < 64) {
      int c = 0;
      for (int j = 0; j < 64; ++j) if (Ash[t * 80 + j] > 1e-15f) ++c;
      d1[t] = 1.f / sqrtf(1.f + (float)c);
    } else if (t < 80) {
      int i = t - 64; int c = 0;
      for (int j = 0; j < 16; ++j) if (Ash[(64 + i) * 80 + 64 + j] > 1e-15f) ++c;
      d2s[i] = 1.f / sqrtf(1.f + (float)c);
    }
    __syncthreads();
    {
      float* an22 = ws + OFF_AN22;
      unsigned short* anH = (unsigned short*)(ws + OFF_ANH);
      unsigned short* anL = (unsigned short*)(ws + OFF_ANL);
      for (int e = t; e < 4096; e += 256) {
        int i = e >> 6, j = e & 63;
        float v = d1[i] * Ash[i * 80 + j] * d1[j];
        unsigned short h = f2bf(v);
        anH[e] = h; anL[e] = f2bf(v - bf2f(h));
      }
      for (int e = t; e < 256; e += 256) {
        int i = e >> 4, j = e & 15;
        an22[e] = d2s[i] * Ash[(64 + i) * 80 + 64 + j] * d2s[j];
      }
    }
    if (t < 16) {
      float* mk = ws + OFF_MK;
      int j = t;
      float m = -3.4e38f;
      for (int i = 0; i < 64; ++i) {
        float v = Ash[(64 + j) * 80 + i];
        v = (v != 0.f) ? v : NEGBIG;
        m = fmaxf(m, v);
      }
      float s = 0.f;
      for (int i = 0; i < 64; ++i) {
        float v = Ash[(64 + j) * 80 + i];
        v = (v != 0.f) ? v : NEGBIG;
        s += expf(v - m);
      }
      float inv = 1.f / s;
      for (int i = 0; i < 64; ++i) {
        float v = Ash[(64 + j) * 80 + i];
        v = (v != 0.f) ? v : NEGBIG;
        mk[j * 64 + i] = (expf(v - m) * inv >= 0.004f) ? 1.f : 0.f;
      }
    }
  } else if (blockIdx.x == 1) {
    unsigned short* wkh = (unsigned short*)(ws + OFF_WKH);
    unsigned short* wkl = (unsigned short*)(ws + OFF_WKL);
    for (int e = t; e < 4096; e += 256) {
      int h = e >> 6, o = e & 63;
      float v = (o < 50) ? Wk[o * 64 + h] : 0.f;
      unsigned short hh = f2bf(v);
      wkh[e] = hh; wkl[e] = f2bf(v - bf2f(hh));
    }
    if (t == 0) {
      float v = sm[0];
      float sig = 1.f / (1.f + expf(-v));
      (ws + OFF_SC)[0] = -0.5f / (sig * 0.01f);
    }
  } else if (blockIdx.x == 2) {
    unsigned short* w1h = (unsigned short*)(ws + OFF_W1H);
    unsigned short* w1l = (unsigned short*)(ws + OFF_W1L);
    for (int e = t; e < 8192; e += 256) {
      int n = e >> 6, k = e & 63;
      float v = (k < 51) ? w1[n * 51 + k] : 0.f;
      unsigned short h = f2bf(v);
      w1h[e] = h; w1l[e] = f2bf(v - bf2f(h));
    }
    unsigned short* w3h = (unsigned short*)(ws + OFF_W3H);
    unsigned short* w3l = (unsigned short*)(ws + OFF_W3L);
    for (int e = t; e < 8192; e += 256) {
      int n = e >> 7, k = e & 127;
      float v = (n < 50) ? w3[n * 128 + k] : 0.f;
      unsigned short h = f2bf(v);
      w3h[e] = h; w3l[e] = f2bf(v - bf2f(h));
    }
    unsigned short* gah = (unsigned short*)(ws + OFF_GAH);
    unsigned short* gal = (unsigned short*)(ws + OFF_GAL);
    for (int e = t; e < 4096; e += 256) {
      int n = e >> 6, k = e & 63;
      float v = (k < 51) ? wg1a[n * 51 + k] : 0.f;
      unsigned short h = f2bf(v);
      gah[e] = h; gal[e] = f2bf(v - bf2f(h));
    }
  } else {
    unsigned short* w2h = (unsigned short*)(ws + OFF_W2H);
    unsigned short* w2l = (unsigned short*)(ws + OFF_W2L);
    for (int e = t; e < 16384; e += 256) {
      int n = e >> 7, k = e & 127;
      float v = w2[n * 128 + k];
      unsigned short h = f2bf(v);
      w2h[e] = h; w2l[e] = f2bf(v - bf2f(h));
    }
    unsigned short* gbh = (unsigned short*)(ws + OFF_GBH);
    unsigned short* gbl = (unsigned short*)(ws + OFF_GBL);
    for (int e = t; e < 4096; e += 256) {
      int n = e >> 6, k = e & 63;
      float v = (n < 50) ? wg1b[n * 64 + k] : 0.f;
      unsigned short h = f2bf(v);
      gbh[e] = h; gbl[e] = f2bf(v - bf2f(h));
    }
    float* g2at = ws + OFF_G2AT;
    for (int e = t; e < 64 * 51; e += 256) { int o = e / 51, k = e % 51; g2at[k * 64 + o] = wg2a[e]; }
  }
}

// ===========================================================================
// k_fused: per-batch MLP + g1 + q + g2 + dist. 512 threads, 1 batch/block.
// LDS map (ushort units, SH[20480] = 40960B = 4 blocks/CU):
//   xcH [0,5120) xcL [5120,10240)   persistent split-bf16 x (80x64);
//                                   block-7 bytes (col 56-63) host misc.
//   b2H [10240,14336) b2L [14336,18432)  single ping-pong (T1/P/Q/x1/Zp)
//   zfH [18432,19456) zfL [19456,20480)
// aliases over b2: mHd (MLP, <=32x128), alS (post-GEMM6), late g2/dist
// scratch. misc: spH2 in xcH row slots; sfS/yhsS in xcL row 0-15 slots.
// ===========================================================================
__global__ __launch_bounds__(512, 8) void k_fused(
    const float* __restrict__ data,
    const float* __restrict__ emb0, const float* __restrict__ emb1,
    const float* __restrict__ emb2,
    const float* __restrict__ b1v, const float* __restrict__ b2v,
    const float* __restrict__ b3v,
    const float* __restrict__ wg2b,
    float* __restrict__ ws, float* __restrict__ out)
{
  __shared__ __align__(16) unsigned short SH[20480];

  unsigned short* xcH = SH;
  unsigned short* xcL = SH + 5120;
  unsigned short* b2H = SH + 10240;
  unsigned short* b2L = SH + 14336;
  unsigned short* zfH = SH + 18432;
  unsigned short* zfL = SH + 19456;
  // aliases over b2
  float* alS = (float*)(SH + 10240);    // 64*17 f (valid after GEMM6)
  unsigned short* mHdH = SH + 10240;    // MLP hidden chunk (<=32x128)
  unsigned short* mHdL = SH + 14336;
  float* X2v  = (float*)(SH + 10240);   // 832 f (valid after yh)
  float* A22v = X2v + 832;              // 256 f
  float* G2v  = A22v + 256;             // 1024 f
  float* Pmv  = G2v + 1024;             // 1024 f
  float* wb2  = Pmv + 1024;             // 64 f
  float* zzv  = wb2 + 64;               // 16 f
  float* sqS  = zzv + 16;               // 80 f
  // misc in xc block-7 free slots (those bytes are never read: zero-frag trick)
#define SPH2(row) ((float*)(xcH + ((row) << 6) + ((((row) & 7) ^ 7) << 3)))
#define MS16(j)   ((float*)(xcL + ((j) << 6) + ((((j) & 7) ^ 7) << 3)))

  const int t = threadIdx.x, b = blockIdx.x;
  const int lane = t & 63, wave = t >> 6;
  const int m16 = lane & 15, quad = lane >> 4;
  const int s = wave & 3, half = wave >> 2;
  const int row0 = s * 16;
  const int arow = row0 + m16;

  const bf16x8 z8 = (bf16x8){0, 0, 0, 0, 0, 0, 0, 0};

  const unsigned short* w1h = (const unsigned short*)(ws + OFF_W1H);
  const unsigned short* w1l = (const unsigned short*)(ws + OFF_W1L);
  const unsigned short* w2h = (const unsigned short*)(ws + OFF_W2H);
  const unsigned short* w2l = (const unsigned short*)(ws + OFF_W2L);
  const unsigned short* w3h = (const unsigned short*)(ws + OFF_W3H);
  const unsigned short* w3l = (const unsigned short*)(ws + OFF_W3L);
  const float* mk = ws + OFF_MK;
  const float* an22 = ws + OFF_AN22;
  const float* g2at = ws + OFF_G2AT;
  const unsigned short* gAnH = (const unsigned short*)(ws + OFF_ANH);
  const unsigned short* gAnL = (const unsigned short*)(ws + OFF_ANL);
  const unsigned short* gaH = (const unsigned short*)(ws + OFF_GAH);
  const unsigned short* gaL = (const unsigned short*)(ws + OFF_GAL);
  const unsigned short* gbH = (const unsigned short*)(ws + OFF_GBH);
  const unsigned short* gbL = (const unsigned short*)(ws + OFF_GBL);
  const unsigned short* gwkH = (const unsigned short*)(ws + OFF_WKH);
  const unsigned short* gwkL = (const unsigned short*)(ws + OFF_WKL);
  const float sc = (ws + OFF_SC)[0];

  // =========================================================================
  // MLP phase: 3 row-chunks (32+32+16); mHd in b2 (16KB). L1 gathers from
  // global; L3 writes split-bf16 into xc (skip col 50 and cols >= 56).
  // =========================================================================
#pragma unroll
  for (int ck = 0; ck < 3; ++ck) {
    const int C0 = ck * 32;
    const int NT = (ck == 2) ? 1 : 2;

    // ---- L1: gather -> MFMA -> relu -> mHd ----
    {
      const int col = wave * 16 + m16;     // 0..127
      const float bias = b1v[col];
      f32x4 acc1[2];
#pragma unroll
      for (int rt = 0; rt < 2; ++rt) acc1[rt] = (f32x4){0.f, 0.f, 0.f, 0.f};
#pragma unroll
      for (int kh = 0; kh < 2; ++kh) {
        bf16x8 bH = *(const bf16x8*)(w1h + (col << 6) + kh * 32 + (quad << 3));
        bf16x8 bL = *(const bf16x8*)(w1l + (col << 6) + kh * 32 + (quad << 3));
#pragma unroll
        for (int rt = 0; rt < 2; ++rt) {
          if (rt >= NT) break;
          const int g = b * 80 + C0 + rt * 16 + m16;
          float v[8];
          if (kh == 0) {
            int i0 = (int)data[g * 6 + 0];
            const float* p = emb0 + i0 * 32 + (quad << 3);
#pragma unroll
            for (int j = 0; j < 8; ++j) v[j] = p[j];
          } else {
            if (quad == 0) {
              int i1 = (int)data[g * 6 + 1];
#pragma unroll
              for (int j = 0; j < 8; ++j) v[j] = emb1[i1 * 8 + j];
            } else if (quad == 1) {
              int i2 = (int)data[g * 6 + 2];
#pragma unroll
              for (int j = 0; j < 8; ++j) v[j] = emb2[i2 * 8 + j];
            } else if (quad == 2) {
              v[0] = data[g * 6 + 3]; v[1] = data[g * 6 + 4]; v[2] = data[g * 6 + 5];
#pragma unroll
              for (int j = 3; j < 8; ++j) v[j] = 0.f;
            } else {
#pragma unroll
              for (int j = 0; j < 8; ++j) v[j] = 0.f;
            }
          }
          bf16x8 aH, aL;
          split8(v, aH, aL);
          MFMA3(acc1[rt], aH, aL, bH, bL)
        }
      }
#pragma unroll
      for (int rt = 0; rt < 2; ++rt) {
        if (rt >= NT) break;
#pragma unroll
        for (int r = 0; r < 4; ++r) {
          float v = acc1[rt][r] + bias; v = v > 0.f ? v : 0.f;
          int idx = SWZ7(rt * 16 + quad * 4 + r, col);
          split2(v, mHdH[idx], mHdL[idx]);
        }
      }
    }
    __syncthreads();

    // ---- L2 compute (accs in regs; two half-K passes) ----
    f32x4 acc2[2];
#pragma unroll
    for (int rt = 0; rt < 2; ++rt) acc2[rt] = (f32x4){0.f, 0.f, 0.f, 0.f};
    {
      const int col = wave * 16 + m16;
#pragma unroll
      for (int kh = 0; kh < 2; ++kh) {
        bf16x8 bh0 = *(const bf16x8*)(w2h + (col << 7) + ((quad + kh * 8) << 3));
        bf16x8 bl0 = *(const bf16x8*)(w2l + (col << 7) + ((quad + kh * 8) << 3));
        bf16x8 bh1 = *(const bf16x8*)(w2h + (col << 7) + ((quad + kh * 8 + 4) << 3));
        bf16x8 bl1 = *(const bf16x8*)(w2l + (col << 7) + ((quad + kh * 8 + 4) << 3));
#pragma unroll
        for (int lrt = 0; lrt < 2; ++lrt) {
          if (lrt >= NT) break;
          const int lr = lrt * 16 + m16;
          int ach0 = ((quad + kh * 8) ^ (m16 & 7)) << 3;
          int ach1 = ((quad + kh * 8 + 4) ^ (m16 & 7)) << 3;
          bf16x8 aH = *(const bf16x8*)(mHdH + (lr << 7) + ach0);
          bf16x8 aL = *(const bf16x8*)(mHdL + (lr << 7) + ach0);
          MFMA3(acc2[lrt], aH, aL, bh0, bl0)
          aH = *(const bf16x8*)(mHdH + (lr << 7) + ach1);
          aL = *(const bf16x8*)(mHdL + (lr << 7) + ach1);
          MFMA3(acc2[lrt], aH, aL, bh1, bl1)
        }
      }
    }
    __syncthreads();

    // ---- L2 writeback (relu -> mHd in place) ----
    {
      const int col = wave * 16 + m16;
      const float bias = b2v[col];
#pragma unroll
      for (int lrt = 0; lrt < 2; ++lrt) {
        if (lrt >= NT) break;
#pragma unroll
        for (int r = 0; r < 4; ++r) {
          float v = acc2[lrt][r] + bias; v = v > 0.f ? v : 0.f;
          int idx = SWZ7(lrt * 16 + quad * 4 + r, col);
          split2(v, mHdH[idx], mHdL[idx]);
        }
      }
    }
    __syncthreads();

    // ---- L3: mHd @ W3^T + b3 -> xc (skip col 50 and cols >= 56) ----
    {
      const int colt = wave & 3, rh = wave >> 2;
      const int col = colt * 16 + m16;     // 0..63
      const float bias = (col < 50) ? b3v[col] : 0.f;
      for (int lrt = rh; lrt < NT; lrt += 2) {
        const int lr = lrt * 16 + m16;
        f32x4 acc = (f32x4){0.f, 0.f, 0.f, 0.f};
#pragma unroll
        for (int kh = 0; kh < 2; ++kh) {
          bf16x8 bh0 = *(const bf16x8*)(w3h + (col << 7) + ((quad + kh * 8) << 3));
          bf16x8 bl0 = *(const bf16x8*)(w3l + (col << 7) + ((quad + kh * 8) << 3));
          bf16x8 bh1 = *(const bf16x8*)(w3h + (col << 7) + ((quad + kh * 8 + 4) << 3));
          bf16x8 bl1 = *(const bf16x8*)(w3l + (col << 7) + ((quad + kh * 8 + 4) << 3));
          int ach0 = ((quad + kh * 8) ^ (m16 & 7)) << 3;
          int ach1 = ((quad + kh * 8 + 4) ^ (m16 & 7)) << 3;
          bf16x8 aH = *(const bf16x8*)(mHdH + (lr << 7) + ach0);
          bf16x8 aL = *(const bf16x8*)(mHdL + (lr << 7) + ach0);
          MFMA3(acc, aH, aL, bh0, bl0)
          aH = *(const bf16x8*)(mHdH + (lr << 7) + ach1);
          aL = *(const bf16x8*)(mHdL + (lr << 7) + ach1);
          MFMA3(acc, aH, aL, bh1, bl1)
        }
        if (col != 50 && col < 56) {
#pragma unroll
          for (int r = 0; r < 4; ++r) {
            int grow = C0 + lrt * 16 + quad * 4 + r;
            int idx = SWZ6(grow, col);
            split2(acc[r] + bias, xcH[idx], xcL[idx]);
          }
        }
      }
      if (ck == 0 && t < 80) {            // col 50: y for rows<64, 0 for 64-79
        float v = (t < 64) ? data[(b * 80 + t) * 6 + 5] : 0.f;
        int idx = SWZ6(t, 50);
        split2(v, xcH[idx], xcL[idx]);
      }
    }
    __syncthreads();
  }
  // xc complete; b2 (mHd) dead.

  // =========================================================================
  // GAT phase. Weights/An from global (TLP hides latency at 4-resident);
  // single ping-pong buffer b2. Zero-frag trick for xc block 7.
  // =========================================================================
  f32x4 accA[2];

  // ---- GEMM1: T1 = sg1(xc rows 0-63) @ W1a^T ----
#pragma unroll
  for (int n = 0; n < 2; ++n) accA[n] = (f32x4){0.f, 0.f, 0.f, 0.f};
#pragma unroll
  for (int kb8 = 0; kb8 < 8; kb8 += 4) {
    int ach = ((quad + kb8) ^ (m16 & 7)) << 3;
    int k0 = (quad + kb8) << 3;
    bf16x8 aH, aL;
    if (kb8 == 4 && quad == 3) { aH = z8; aL = z8; }
    else {
      aH = *(const bf16x8*)(xcH + (arow << 6) + ach);
      aL = *(const bf16x8*)(xcL + (arow << 6) + ach);
    }
#pragma unroll
    for (int n = 0; n < 2; ++n) {
      const int col = (half * 2 + n) * 16 + m16;
      bf16x8 bH = *(const bf16x8*)(gaH + (col << 6) + k0);
      bf16x8 bL = *(const bf16x8*)(gaL + (col << 6) + k0);
      MFMA3(accA[n], aH, aL, bH, bL)
    }
  }
  // E1: T1 -> b2 [col][k]
  {
    const int kb = row0 + quad * 4;
#pragma unroll
    for (int n = 0; n < 2; ++n) {
      const int col = (half * 2 + n) * 16 + m16;
      int idx = (col << 6) + (((((kb >> 3) ^ (col & 7)) << 3)) | (kb & 7));
      s16x4 hv, lv;
#pragma unroll
      for (int r = 0; r < 4; ++r) {
        unsigned short hh, ll; split2(accA[n][r], hh, ll);
        hv[r] = (short)hh; lv[r] = (short)ll;
      }
      *(s16x4*)(b2H + idx) = hv; *(s16x4*)(b2L + idx) = lv;
    }
  }
  __syncthreads();   // S9

  // ---- GEMM2: P = relu(An @ T1) ----
#pragma unroll
  for (int n = 0; n < 2; ++n) accA[n] = (f32x4){0.f, 0.f, 0.f, 0.f};
#pragma unroll
  for (int kb8 = 0; kb8 < 8; kb8 += 4) {
    int ach = ((quad + kb8) ^ (m16 & 7)) << 3;
    int k0 = (quad + kb8) << 3;
    bf16x8 aH = *(const bf16x8*)(gAnH + (arow << 6) + k0);
    bf16x8 aL = *(const bf16x8*)(gAnL + (arow << 6) + k0);
#pragma unroll
    for (int n = 0; n < 2; ++n) {
      const int col = (half * 2 + n) * 16 + m16;
      int boff = (col << 6) + ach;
      bf16x8 bH = *(const bf16x8*)(b2H + boff);
      bf16x8 bL = *(const bf16x8*)(b2L + boff);
      MFMA3(accA[n], aH, aL, bH, bL)
    }
  }
  __syncthreads();   // S10 (b2 reads done)

  // E2: P -> b2
  {
    const int kb = row0 + quad * 4;
#pragma unroll
    for (int n = 0; n < 2; ++n) {
      const int col = (half * 2 + n) * 16 + m16;
      int idx = (col << 6) + (((((kb >> 3) ^ (col & 7)) << 3)) | (kb & 7));
      s16x4 hv, lv;
#pragma unroll
      for (int r = 0; r < 4; ++r) {
        float v = accA[n][r]; v = v > 0.f ? v : 0.f;
        unsigned short hh, ll; split2(v, hh, ll);
        hv[r] = (short)hh; lv[r] = (short)ll;
      }
      *(s16x4*)(b2H + idx) = hv; *(s16x4*)(b2L + idx) = lv;
    }
  }
  __syncthreads();   // S11

  // ---- GEMM3: Q = An @ P ----
#pragma unroll
  for (int n = 0; n < 2; ++n) accA[n] = (f32x4){0.f, 0.f, 0.f, 0.f};
#pragma unroll
  for (int kb8 = 0; kb8 < 8; kb8 += 4) {
    int ach = ((quad + kb8) ^ (m16 & 7)) << 3;
    int k0 = (quad + kb8) << 3;
    bf16x8 aH = *(const bf16x8*)(gAnH + (arow << 6) + k0);
    bf16x8 aL = *(const bf16x8*)(gAnL + (arow << 6) + k0);
#pragma unroll
    for (int n = 0; n < 2; ++n) {
      const int col = (half * 2 + n) * 16 + m16;
      int boff = (col << 6) + ach;
      bf16x8 bH = *(const bf16x8*)(b2H + boff);
      bf16x8 bL = *(const bf16x8*)(b2L + boff);
      MFMA3(accA[n], aH, aL, bH, bL)
    }
  }
  __syncthreads();   // S12 (b2 reads done)

  // E3: Q -> b2 [row][k]
#pragma unroll
  for (int n = 0; n < 2; ++n) {
    const int col = (half * 2 + n) * 16 + m16;
#pragma unroll
    for (int r = 0; r < 4; ++r) {
      int idx = SWZ6(row0 + quad * 4 + r, col);
      split2(accA[n][r], b2H[idx], b2L[idx]);
    }
  }
  __syncthreads();   // S13

  // ---- GEMM4: x1 = Q @ W1b^T ----
#pragma unroll
  for (int n = 0; n < 2; ++n) accA[n] = (f32x4){0.f, 0.f, 0.f, 0.f};
#pragma unroll
  for (int kb8 = 0; kb8 < 8; kb8 += 4) {
    int ach = ((quad + kb8) ^ (m16 & 7)) << 3;
    int k0 = (quad + kb8) << 3;
    bf16x8 aH = *(const bf16x8*)(b2H + (arow << 6) + ach);
    bf16x8 aL = *(const bf16x8*)(b2L + (arow << 6) + ach);
#pragma unroll
    for (int n = 0; n < 2; ++n) {
      const int col = (half * 2 + n) * 16 + m16;
      bf16x8 bH = *(const bf16x8*)(gbH + (col << 6) + k0);
      bf16x8 bL = *(const bf16x8*)(gbL + (col << 6) + k0);
      MFMA3(accA[n], aH, aL, bH, bL)
    }
  }
  __syncthreads();   // S14 (b2 reads done)

  // E4: x1 -> b2 [row][k]
#pragma unroll
  for (int n = 0; n < 2; ++n) {
    const int col = (half * 2 + n) * 16 + m16;
#pragma unroll
    for (int r = 0; r < 4; ++r) {
      int idx = SWZ6(row0 + quad * 4 + r, col);
      split2(accA[n][r], b2H[idx], b2L[idx]);
    }
  }
  __syncthreads();   // S15

  // ---- GEMM5: Zp = x1 @ WkT (4-term); half0 also Zf = xc[64:80] @ WkT ----
#pragma unroll
  for (int n = 0; n < 2; ++n) accA[n] = (f32x4){0.f, 0.f, 0.f, 0.f};
  f32x4 af = (f32x4){0.f, 0.f, 0.f, 0.f};
#pragma unroll
  for (int kb8 = 0; kb8 < 8; kb8 += 4) {
    int ach = ((quad + kb8) ^ (m16 & 7)) << 3;
    int k0 = (quad + kb8) << 3;
    bf16x8 aH = *(const bf16x8*)(b2H + (arow << 6) + ach);
    bf16x8 aL = *(const bf16x8*)(b2L + (arow << 6) + ach);
#pragma unroll
    for (int n = 0; n < 2; ++n) {
      const int col = (half * 2 + n) * 16 + m16;
      bf16x8 bH = *(const bf16x8*)(gwkH + (col << 6) + k0);
      bf16x8 bL = *(const bf16x8*)(gwkL + (col << 6) + k0);
      MFMA4(accA[n], aH, aL, bH, bL)
    }
  }
  if (half == 0) {
#pragma unroll
    for (int kb8 = 0; kb8 < 8; kb8 += 4) {
      int ach = ((quad + kb8) ^ (m16 & 7)) << 3;
      int k0 = (quad + kb8) << 3;
      bf16x8 aH, aL;
      if (kb8 == 4 && quad == 3) { aH = z8; aL = z8; }
      else {
        aH = *(const bf16x8*)(xcH + ((64 + m16) << 6) + ach);
        aL = *(const bf16x8*)(xcL + ((64 + m16) << 6) + ach);
      }
      const int col = s * 16 + m16;
      bf16x8 bH = *(const bf16x8*)(gwkH + (col << 6) + k0);
      bf16x8 bL = *(const bf16x8*)(gwkL + (col << 6) + k0);
      MFMA4(af, aH, aL, bH, bL)
    }
  }
  float s2r[4];
#pragma unroll
  for (int r = 0; r < 4; ++r)
    s2r[r] = accA[0][r] * accA[0][r] + accA[1][r] * accA[1][r];
#pragma unroll
  for (int m = 1; m < 16; m <<= 1)
#pragma unroll
    for (int r = 0; r < 4; ++r) s2r[r] += __shfl_xor(s2r[r], m);
  __syncthreads();   // S16 (b2 x1 reads done)

  // E5: Zp -> b2 [row][k]; zf (half0); spH2 -> xc slots (m16==0)
#pragma unroll
  for (int n = 0; n < 2; ++n) {
    const int h = (half * 2 + n) * 16 + m16;
#pragma unroll
    for (int r = 0; r < 4; ++r) {
      int idx = SWZ6(row0 + quad * 4 + r, h);
      split2(accA[n][r], b2H[idx], b2L[idx]);
    }
  }
  if (half == 0) {
    const int h = s * 16 + m16;
#pragma unroll
    for (int r = 0; r < 4; ++r) {
      int idx = SWZ6(quad * 4 + r, h);
      split2(af[r], zfH[idx], zfL[idx]);
    }
  }
  if (m16 == 0) {
#pragma unroll
    for (int r = 0; r < 4; ++r)
      SPH2(row0 + quad * 4 + r)[half] = s2r[r];
  }
  __syncthreads();   // S17

  // ---- GEMM6 (half0): cross = Zp @ Zf^T || sfS (half1) ----
  f32x4 ac2 = (f32x4){0.f, 0.f, 0.f, 0.f};
  if (half == 0) {
#pragma unroll
    for (int kb8 = 0; kb8 < 8; kb8 += 4) {
      int ach = ((quad + kb8) ^ (m16 & 7)) << 3;
      bf16x8 aH = *(const bf16x8*)(b2H + (arow << 6) + ach);
      bf16x8 aL = *(const bf16x8*)(b2L + (arow << 6) + ach);
      bf16x8 bH = *(const bf16x8*)(zfH + (m16 << 6) + ach);
      bf16x8 bL = *(const bf16x8*)(zfL + (m16 << 6) + ach);
      MFMA4(ac2, aH, aL, bH, bL)
    }
  } else {
    int idx = t - 256;
    int j = idx >> 4, h0 = (idx & 15) << 2;
    float p = 0.f;
#pragma unroll
    for (int r = 0; r < 4; ++r) {
      int ii = SWZ6(j, h0 + r);
      float v = bf2f(zfH[ii]) + bf2f(zfL[ii]);
      p += v * v;
    }
#pragma unroll
    for (int m = 1; m < 16; m <<= 1) p += __shfl_xor(p, m);
    if ((idx & 15) == 0) MS16(j)[0] = p;
  }
  __syncthreads();   // S18 (Zp reads done; b2 -> alS)

  // ---- alS write (b2 alias) ----
  if (half == 0) {
#pragma unroll
    for (int r = 0; r < 4; ++r) {
      int i = row0 + quad * 4 + r;
      alS[i * 17 + m16] = sc * ((SPH2(i)[0] + SPH2(i)[1]) + MS16(m16)[0] - 2.f * ac2[r]);
    }
  }
  __syncthreads();   // S19

  // ---- masked softmax over j per i ----
  if (t < 64) {
    const int i = t;
    float lv[16];
    float m = -3.4e38f;
#pragma unroll
    for (int j = 0; j < 16; ++j) {
      float v = (mk[j * 64 + i] != 0.f) ? alS[i * 17 + j] : NEGBIG;
      lv[j] = v;
      m = fmaxf(m, v);
    }
    float ssum = 0.f;
#pragma unroll
    for (int j = 0; j < 16; ++j) { lv[j] = expf(lv[j] - m); ssum += lv[j]; }
    float inv = 1.f / ssum;
#pragma unroll
    for (int j = 0; j < 16; ++j) alS[i * 17 + j] = lv[j] * inv;
  }
  __syncthreads();   // S20

  // ---- yh: 16 j x 16 lanes, 4 i each; yv from xc col 50 ----
  if (t < 256) {
    int j = t >> 4, i0 = (t & 15) << 2;
    float p = 0.f;
#pragma unroll
    for (int r = 0; r < 4; ++r) {
      int i = i0 + r;
      int iy = SWZ6(i, 50);
      float yv = bf2f(xcH[iy]) + bf2f(xcL[iy]);
      p += alS[i * 17 + j] * yv;
    }
#pragma unroll
    for (int m = 1; m < 16; m <<= 1) p += __shfl_xor(p, m);
    if ((t & 15) == 0) MS16(j)[1] = p;
  }
  __syncthreads();   // S21 (alS dead)

  // ---- xc col50 fixup (rows 64-79 <- yh); X2v/A22v/wb2 staging (b2 alias) ----
  if (t < 16) {
    int idx = SWZ6(64 + t, 50);
    split2(MS16(t)[1], xcH[idx], xcL[idx]);
  }
  for (int e = t; e < 832; e += 512) {
    int r = e / 52, c = e - r * 52;
    float v = 0.f;
    if (c < 50) {
      int i6 = SWZ6(64 + r, c);
      v = bf2f(xcH[i6]) + bf2f(xcL[i6]);
    } else if (c == 50) v = MS16(r)[1];
    X2v[e] = v;
  }
  for (int e = t; e < 256; e += 512) A22v[e] = an22[e];
  if (t < 64) wb2[t] = wg2b[t];
  __syncthreads();   // S22

  // ---- Phase A: diag Gram tiles -> sqS (waves 0-4) || G2v (waves 5-7) ----
  if (wave < 5) {
    const int ts = wave;
    f32x4 acc = (f32x4){0.f, 0.f, 0.f, 0.f};
#pragma unroll
    for (int kb8 = 0; kb8 < 8; kb8 += 4) {
      int ach = ((quad + kb8) ^ (m16 & 7)) << 3;
      bf16x8 aH, aL;
      if (kb8 == 4 && quad == 3) { aH = z8; aL = z8; }
      else {
        aH = *(const bf16x8*)(xcH + ((ts * 16 + m16) << 6) + ach);
        aL = *(const bf16x8*)(xcL + ((ts * 16 + m16) << 6) + ach);
      }
      MFMA3(acc, aH, aL, aH, aL)
    }
    if ((m16 >> 2) == quad) sqS[ts * 16 + m16] = acc[m16 & 3];
  } else {
    for (int e = t - 320; e < 1024; e += 192) {
      int j = e >> 6, h = e & 63;
      float ssum = 0.f;
      for (int k = 0; k < 51; ++k) ssum += X2v[j * 52 + k] * g2at[k * 64 + h];
      G2v[e] = ssum;
    }
  }
  __syncthreads();   // S23 (sqS + G2v visible)

  // ---- Phase B: all 25 Gram tiles, epilogue+store inline; Pmv ----
  {
    float* dist = out + OUT_DIST + b * 6400;
    for (int idx = wave; idx < 25; idx += 8) {
      int ts = idx / 5, tf = idx - ts * 5;
      f32x4 acc = (f32x4){0.f, 0.f, 0.f, 0.f};
#pragma unroll
      for (int kb8 = 0; kb8 < 8; kb8 += 4) {
        int ach = ((quad + kb8) ^ (m16 & 7)) << 3;
        bf16x8 aH, aL, bH, bL;
        if (kb8 == 4 && quad == 3) { aH = z8; aL = z8; bH = z8; bL = z8; }
        else {
          aH = *(const bf16x8*)(xcH + ((ts * 16 + m16) << 6) + ach);
          aL = *(const bf16x8*)(xcL + ((ts * 16 + m16) << 6) + ach);
          const int col = tf * 16 + m16;
          bH = *(const bf16x8*)(xcH + (col << 6) + ach);
          bL = *(const bf16x8*)(xcL + (col << 6) + ach);
        }
        MFMA3(acc, aH, aL, bH, bL)
      }
#pragma unroll
      for (int r = 0; r < 4; ++r) {
        int i = ts * 16 + quad * 4 + r;
        int m = tf * 16 + m16;
        float d2 = sqS[i] + sqS[m] - 2.f * acc[r];
        d2 = d2 > 0.f ? d2 : 0.f;
        dist[i * 80 + m] = d2 > 0.f ? sqrtf(d2) : 0.f;
      }
    }
  }
  for (int e = t; e < 1024; e += 512) {
    int j = e >> 6, h = e & 63;
    float ssum = 0.f;
#pragma unroll
    for (int k = 0; k < 16; ++k) ssum += A22v[j * 16 + k] * G2v[k * 64 + h];
    Pmv[e] = ssum > 0.f ? ssum : 0.f;
  }
  __syncthreads();   // S24
  if (t < 256) {
    int j = t >> 4, h0 = (t & 15) << 2;
    float p = 0.f;
#pragma unroll
    for (int r = 0; r < 4; ++r) p += Pmv[j * 64 + h0 + r] * wb2[h0 + r];
#pragma unroll
    for (int m = 1; m < 16; m <<= 1) p += __shfl_xor(p, m);
    if ((t & 15) == 0) zzv[j] = p;
  }
  __syncthreads();   // S25
  if (t < 16) {
    float ssum = 0.f;
#pragma unroll
    for (int k = 0; k < 16; ++k) ssum += A22v[t * 16 + k] * zzv[k];
    out[OUT_OUT + b * 16 + t] = ssum;
  }
}

// ===========================================================================
extern "C" void kernel_launch(void* const* d_in, const int* in_sizes, int n_in,
                              void* d_out, int out_size, void* d_ws, size_t ws_size,
                              hipStream_t stream)
{
  const float* data = (const float*)d_in[0];
  const float* emb0 = (const float*)d_in[1];
  const float* emb1 = (const float*)d_in[2];
  const float* emb2 = (const float*)d_in[3];
  const float* w1   = (const float*)d_in[4];
  const float* b1   = (const float*)d_in[5];
  const float* w2   = (const float*)d_in[6];
  const float* b2   = (const float*)d_in[7];
  const float* w3   = (const float*)d_in[8];
  const float* b3   = (const float*)d_in[9];
  const float* M    = (const float*)d_in[10];
  const float* wg1a = (const float*)d_in[11];
  const float* wg1b = (const float*)d_in[12];
  const float* Wk   = (const float*)d_in[13];
  const float* smo  = (const float*)d_in[14];
  const float* wg2a = (const float*)d_in[15];
  const float* wg2b = (const float*)d_in[16];
  float* ws  = (float*)d_ws;
  float* out = (float*)d_out;

  k_prep <<<dim3(4),    dim3(256), 0, stream>>>(M, Wk, smo, w1, w2, w3, wg1a, wg1b, wg2a, ws, out);
  k_fused<<<dim3(1024), dim3(512), 0, stream>>>(data, emb0, emb1, emb2, b1, b2, b3, wg2b, ws, out);
}

// Round 9
// 244.497 us; speedup vs baseline: 1.1115x; 1.1115x over previous
//
#include <hip/hip_runtime.h>
#include <math.h>

// ---------------------------------------------------------------------------
// GAT_23613730193923 — round 18: round 17 with the register cap removed.
// r17 proved 4 blocks/CU materializes at LDS=40960 (occupancy 41->78%) but
// __launch_bounds__(512,8)'s hard 64-VGPR cap forced wholesale spill
// (WRITE 134MB). launch_bounds only constrains the ALLOCATOR; hardware
// residency follows actual VGPR. Natural allocation was 64 in r14-16, so
// with (512,4) the allocator is unconstrained and 8 waves/SIMD = 4 blocks
// should still be scheduled by HW if it lands <=64. Only change: (512,4).
// ---------------------------------------------------------------------------

#define NEGBIG (-1e30f)

// ---- workspace offsets (floats) ----
#define OFF_A     7471104    // 80*80
#define OFF_AN22  7481600    // 16*16
#define OFF_MK    7484356    // 16*64
#define OFF_GAH   7514692    // W1a hi: 64*64 ushort
#define OFF_GAL   7516740
#define OFF_G2AT  7521156    // 51*64 fp32
#define OFF_SC    7524420    // 1
#define OFF_W1H   7524424    // 128*64 ushort
#define OFF_W1L   7528520
#define OFF_W2H   7532616    // 128*128 ushort
#define OFF_W2L   7540808
#define OFF_W3H   7549000    // 64*128 ushort
#define OFF_W3L   7553096
#define OFF_ANH   7557192    // An11 hi: 64*64 ushort
#define OFF_ANL   7559240
#define OFF_GBH   7561288    // W1b hi: 64*64 ushort
#define OFF_GBL   7563336
#define OFF_WKH   7565384    // Wk^T hi: [h=64][o=64] ushort
#define OFF_WKL   7567432

// ---- output offsets (floats): (out B*16, dist B*6400, A 6400) ----
#define OUT_OUT   0
#define OUT_DIST  16384
#define OUT_A     6569984

typedef __attribute__((ext_vector_type(8))) short bf16x8;
typedef __attribute__((ext_vector_type(4))) short s16x4;
typedef __attribute__((ext_vector_type(4))) float f32x4;

__device__ __forceinline__ unsigned short f2bf(float x) {  // RTN
  union { float f; unsigned u; } v; v.f = x;
  unsigned r = v.u + 0x7fffu + ((v.u >> 16) & 1u);
  return (unsigned short)(r >> 16);
}
__device__ __forceinline__ float bf2f(unsigned short h) {
  union { unsigned u; float f; } v; v.u = ((unsigned)h) << 16; return v.f;
}
__device__ __forceinline__ void split2(float v, unsigned short& h, unsigned short& l) {
  unsigned short hh = f2bf(v);
  h = hh;
  l = f2bf(v - bf2f(hh));
}
__device__ __forceinline__ void split8(const float* v, bf16x8& h8, bf16x8& l8) {
#pragma unroll
  for (int j = 0; j < 8; ++j) {
    unsigned short hh, ll; split2(v[j], hh, ll);
    h8[j] = (short)hh; l8[j] = (short)ll;
  }
}
#define SWZ6(r, k) (((r) << 6) + (((((k) >> 3) ^ ((r) & 7)) << 3) | ((k) & 7)))
#define SWZ7(r, k) (((r) << 7) + (((((k) >> 3) ^ ((r) & 7)) << 3) | ((k) & 7)))

#define MFMA3(acc, aH, aL, bH, bL) \
  acc = __builtin_amdgcn_mfma_f32_16x16x32_bf16(aH, bH, acc, 0, 0, 0); \
  acc = __builtin_amdgcn_mfma_f32_16x16x32_bf16(aH, bL, acc, 0, 0, 0); \
  acc = __builtin_amdgcn_mfma_f32_16x16x32_bf16(aL, bH, acc, 0, 0, 0);
#define MFMA4(acc, aH, aL, bH, bL) \
  MFMA3(acc, aH, aL, bH, bL) \
  acc = __builtin_amdgcn_mfma_f32_16x16x32_bf16(aL, bL, acc, 0, 0, 0);

// ===========================================================================
// k_prep (unchanged)
// ===========================================================================
__global__ __launch_bounds__(256) void k_prep(
    const float* __restrict__ M, const float* __restrict__ Wk,
    const float* __restrict__ sm,
    const float* __restrict__ w1, const float* __restrict__ w2,
    const float* __restrict__ w3,
    const float* __restrict__ wg1a, const float* __restrict__ wg1b,
    const float* __restrict__ wg2a,
    float* __restrict__ ws, float* __restrict__ out)
{
  __shared__ float Msh[80 * 26];
  __shared__ float Ash[80 * 80];
  __shared__ float d1[64];
  __shared__ float d2s[16];
  const int t = threadIdx.x;

  if (blockIdx.x == 0) {
    for (int e = t; e < 80 * 26; e += 256) Msh[e] = M[e];
    __syncthreads();
    for (int e = t; e < 6400; e += 256) {
      int i = e / 80, j = e % 80;
      float v = 0.f;
      if (j < i) {
        float s = 0.f;
        for (int k = 0; k < 26; ++k) s += Msh[i * 26 + k] * Msh[j * 26 + k];
        v = s > 0.f ? s : 0.f;
      }
      Ash[e] = v;
    }
    __syncthreads();
    if (t > 0 && t < 80) {
      int i = t;
      float m = -3.4e38f;
      for (int j = 0; j < i; ++j) m = fmaxf(m, Ash[i * 80 + j]);
      float s = 0.f;
      for (int j = 0; j < i; ++j) {
        float e = expf(Ash[i * 80 + j] - m);
        Ash[i * 80 + j] = e;
        s += e;
      }
      float inv = 1.f / s;
      for (int j = 0; j < i; ++j) Ash[i * 80 + j] *= inv;
    }
    __syncthreads();
    {
      float* Aws = ws + OFF_A;
      float* Aout = out + OUT_A;
      for (int e = t; e < 6400; e += 256) { Aws[e] = Ash[e]; Aout[e] = Ash[e]; }
    }
    if (t < 64) {
      int c = 0;
      for (int j = 0; j < 64; ++j) if (Ash[t * 80 + j] > 1e-15f) ++c;
      d1[t] = 1.f / sqrtf(1.f + (float)c);
    } else if (t < 80) {
      int i = t - 64; int c = 0;
      for (int j = 0; j < 16; ++j) if (Ash[(64 + i) * 80 + 64 + j] > 1e-15f) ++c;
      d2s[i] = 1.f / sqrtf(1.f + (float)c);
    }
    __syncthreads();
    {
      float* an22 = ws + OFF_AN22;
      unsigned short* anH = (unsigned short*)(ws + OFF_ANH);
      unsigned short* anL = (unsigned short*)(ws + OFF_ANL);
      for (int e = t; e < 4096; e += 256) {
        int i = e >> 6, j = e & 63;
        float v = d1[i] * Ash[i * 80 + j] * d1[j];
        unsigned short h = f2bf(v);
        anH[e] = h; anL[e] = f2bf(v - bf2f(h));
      }
      for (int e = t; e < 256; e += 256) {
        int i = e >> 4, j = e & 15;
        an22[e] = d2s[i] * Ash[(64 + i) * 80 + 64 + j] * d2s[j];
      }
    }
    if (t < 16) {
      float* mk = ws + OFF_MK;
      int j = t;
      float m = -3.4e38f;
      for (int i = 0; i < 64; ++i) {
        float v = Ash[(64 + j) * 80 + i];
        v = (v != 0.f) ? v : NEGBIG;
        m = fmaxf(m, v);
      }
      float s = 0.f;
      for (int i = 0; i < 64; ++i) {
        float v = Ash[(64 + j) * 80 + i];
        v = (v != 0.f) ? v : NEGBIG;
        s += expf(v - m);
      }
      float inv = 1.f / s;
      for (int i = 0; i < 64; ++i) {
        float v = Ash[(64 + j) * 80 + i];
        v = (v != 0.f) ? v : NEGBIG;
        mk[j * 64 + i] = (expf(v - m) * inv >= 0.004f) ? 1.f : 0.f;
      }
    }
  } else if (blockIdx.x == 1) {
    unsigned short* wkh = (unsigned short*)(ws + OFF_WKH);
    unsigned short* wkl = (unsigned short*)(ws + OFF_WKL);
    for (int e = t; e < 4096; e += 256) {
      int h = e >> 6, o = e & 63;
      float v = (o < 50) ? Wk[o * 64 + h] : 0.f;
      unsigned short hh = f2bf(v);
      wkh[e] = hh; wkl[e] = f2bf(v - bf2f(hh));
    }
    if (t == 0) {
      float v = sm[0];
      float sig = 1.f / (1.f + expf(-v));
      (ws + OFF_SC)[0] = -0.5f / (sig * 0.01f);
    }
  } else if (blockIdx.x == 2) {
    unsigned short* w1h = (unsigned short*)(ws + OFF_W1H);
    unsigned short* w1l = (unsigned short*)(ws + OFF_W1L);
    for (int e = t; e < 8192; e += 256) {
      int n = e >> 6, k = e & 63;
      float v = (k < 51) ? w1[n * 51 + k] : 0.f;
      unsigned short h = f2bf(v);
      w1h[e] = h; w1l[e] = f2bf(v - bf2f(h));
    }
    unsigned short* w3h = (unsigned short*)(ws + OFF_W3H);
    unsigned short* w3l = (unsigned short*)(ws + OFF_W3L);
    for (int e = t; e < 8192; e += 256) {
      int n = e >> 7, k = e & 127;
      float v = (n < 50) ? w3[n * 128 + k] : 0.f;
      unsigned short h = f2bf(v);
      w3h[e] = h; w3l[e] = f2bf(v - bf2f(h));
    }
    unsigned short* gah = (unsigned short*)(ws + OFF_GAH);
    unsigned short* gal = (unsigned short*)(ws + OFF_GAL);
    for (int e = t; e < 4096; e += 256) {
      int n = e >> 6, k = e & 63;
      float v = (k < 51) ? wg1a[n * 51 + k] : 0.f;
      unsigned short h = f2bf(v);
      gah[e] = h; gal[e] = f2bf(v - bf2f(h));
    }
  } else {
    unsigned short* w2h = (unsigned short*)(ws + OFF_W2H);
    unsigned short* w2l = (unsigned short*)(ws + OFF_W2L);
    for (int e = t; e < 16384; e += 256) {
      int n = e >> 7, k = e & 127;
      float v = w2[n * 128 + k];
      unsigned short h = f2bf(v);
      w2h[e] = h; w2l[e] = f2bf(v - bf2f(h));
    }
    unsigned short* gbh = (unsigned short*)(ws + OFF_GBH);
    unsigned short* gbl = (unsigned short*)(ws + OFF_GBL);
    for (int e = t; e < 4096; e += 256) {
      int n = e >> 6, k = e & 63;
      float v = (n < 50) ? wg1b[n * 64 + k] : 0.f;
      unsigned short h = f2bf(v);
      gbh[e] = h; gbl[e] = f2bf(v - bf2f(h));
    }
    float* g2at = ws + OFF_G2AT;
    for (int e = t; e < 64 * 51; e += 256) { int o = e / 51, k = e % 51; g2at[k * 64 + o] = wg2a[e]; }
  }
}

// ===========================================================================
// k_fused: per-batch MLP + g1 + q + g2 + dist. 512 threads, 1 batch/block.
// LDS map (ushort units, SH[20480] = 40960B = 4 blocks/CU):
//   xcH [0,5120) xcL [5120,10240)   persistent split-bf16 x (80x64);
//                                   block-7 bytes (col 56-63) host misc.
//   b2H [10240,14336) b2L [14336,18432)  single ping-pong (T1/P/Q/x1/Zp)
//   zfH [18432,19456) zfL [19456,20480)
// aliases over b2: mHd (MLP, <=32x128), alS (post-GEMM6), late g2/dist
// scratch. misc: spH2 in xcH row slots; sfS/yhsS in xcL row 0-15 slots.
// ===========================================================================
__global__ __launch_bounds__(512, 4) void k_fused(
    const float* __restrict__ data,
    const float* __restrict__ emb0, const float* __restrict__ emb1,
    const float* __restrict__ emb2,
    const float* __restrict__ b1v, const float* __restrict__ b2v,
    const float* __restrict__ b3v,
    const float* __restrict__ wg2b,
    float* __restrict__ ws, float* __restrict__ out)
{
  __shared__ __align__(16) unsigned short SH[20480];

  unsigned short* xcH = SH;
  unsigned short* xcL = SH + 5120;
  unsigned short* b2H = SH + 10240;
  unsigned short* b2L = SH + 14336;
  unsigned short* zfH = SH + 18432;
  unsigned short* zfL = SH + 19456;
  // aliases over b2
  float* alS = (float*)(SH + 10240);    // 64*17 f (valid after GEMM6)
  unsigned short* mHdH = SH + 10240;    // MLP hidden chunk (<=32x128)
  unsigned short* mHdL = SH + 14336;
  float* X2v  = (float*)(SH + 10240);   // 832 f (valid after yh)
  float* A22v = X2v + 832;              // 256 f
  float* G2v  = A22v + 256;             // 1024 f
  float* Pmv  = G2v + 1024;             // 1024 f
  float* wb2  = Pmv + 1024;             // 64 f
  float* zzv  = wb2 + 64;               // 16 f
  float* sqS  = zzv + 16;               // 80 f
  // misc in xc block-7 free slots (those bytes are never read: zero-frag trick)
#define SPH2(row) ((float*)(xcH + ((row) << 6) + ((((row) & 7) ^ 7) << 3)))
#define MS16(j)   ((float*)(xcL + ((j) << 6) + ((((j) & 7) ^ 7) << 3)))

  const int t = threadIdx.x, b = blockIdx.x;
  const int lane = t & 63, wave = t >> 6;
  const int m16 = lane & 15, quad = lane >> 4;
  const int s = wave & 3, half = wave >> 2;
  const int row0 = s * 16;
  const int arow = row0 + m16;

  const bf16x8 z8 = (bf16x8){0, 0, 0, 0, 0, 0, 0, 0};

  const unsigned short* w1h = (const unsigned short*)(ws + OFF_W1H);
  const unsigned short* w1l = (const unsigned short*)(ws + OFF_W1L);
  const unsigned short* w2h = (const unsigned short*)(ws + OFF_W2H);
  const unsigned short* w2l = (const unsigned short*)(ws + OFF_W2L);
  const unsigned short* w3h = (const unsigned short*)(ws + OFF_W3H);
  const unsigned short* w3l = (const unsigned short*)(ws + OFF_W3L);
  const float* mk = ws + OFF_MK;
  const float* an22 = ws + OFF_AN22;
  const float* g2at = ws + OFF_G2AT;
  const unsigned short* gAnH = (const unsigned short*)(ws + OFF_ANH);
  const unsigned short* gAnL = (const unsigned short*)(ws + OFF_ANL);
  const unsigned short* gaH = (const unsigned short*)(ws + OFF_GAH);
  const unsigned short* gaL = (const unsigned short*)(ws + OFF_GAL);
  const unsigned short* gbH = (const unsigned short*)(ws + OFF_GBH);
  const unsigned short* gbL = (const unsigned short*)(ws + OFF_GBL);
  const unsigned short* gwkH = (const unsigned short*)(ws + OFF_WKH);
  const unsigned short* gwkL = (const unsigned short*)(ws + OFF_WKL);
  const float sc = (ws + OFF_SC)[0];

  // =========================================================================
  // MLP phase: 3 row-chunks (32+32+16); mHd in b2 (16KB). L1 gathers from
  // global; L3 writes split-bf16 into xc (skip col 50 and cols >= 56).
  // =========================================================================
#pragma unroll
  for (int ck = 0; ck < 3; ++ck) {
    const int C0 = ck * 32;
    const int NT = (ck == 2) ? 1 : 2;

    // ---- L1: gather -> MFMA -> relu -> mHd ----
    {
      const int col = wave * 16 + m16;     // 0..127
      const float bias = b1v[col];
      f32x4 acc1[2];
#pragma unroll
      for (int rt = 0; rt < 2; ++rt) acc1[rt] = (f32x4){0.f, 0.f, 0.f, 0.f};
#pragma unroll
      for (int kh = 0; kh < 2; ++kh) {
        bf16x8 bH = *(const bf16x8*)(w1h + (col << 6) + kh * 32 + (quad << 3));
        bf16x8 bL = *(const bf16x8*)(w1l + (col << 6) + kh * 32 + (quad << 3));
#pragma unroll
        for (int rt = 0; rt < 2; ++rt) {
          if (rt >= NT) break;
          const int g = b * 80 + C0 + rt * 16 + m16;
          float v[8];
          if (kh == 0) {
            int i0 = (int)data[g * 6 + 0];
            const float* p = emb0 + i0 * 32 + (quad << 3);
#pragma unroll
            for (int j = 0; j < 8; ++j) v[j] = p[j];
          } else {
            if (quad == 0) {
              int i1 = (int)data[g * 6 + 1];
#pragma unroll
              for (int j = 0; j < 8; ++j) v[j] = emb1[i1 * 8 + j];
            } else if (quad == 1) {
              int i2 = (int)data[g * 6 + 2];
#pragma unroll
              for (int j = 0; j < 8; ++j) v[j] = emb2[i2 * 8 + j];
            } else if (quad == 2) {
              v[0] = data[g * 6 + 3]; v[1] = data[g * 6 + 4]; v[2] = data[g * 6 + 5];
#pragma unroll
              for (int j = 3; j < 8; ++j) v[j] = 0.f;
            } else {
#pragma unroll
              for (int j = 0; j < 8; ++j) v[j] = 0.f;
            }
          }
          bf16x8 aH, aL;
          split8(v, aH, aL);
          MFMA3(acc1[rt], aH, aL, bH, bL)
        }
      }
#pragma unroll
      for (int rt = 0; rt < 2; ++rt) {
        if (rt >= NT) break;
#pragma unroll
        for (int r = 0; r < 4; ++r) {
          float v = acc1[rt][r] + bias; v = v > 0.f ? v : 0.f;
          int idx = SWZ7(rt * 16 + quad * 4 + r, col);
          split2(v, mHdH[idx], mHdL[idx]);
        }
      }
    }
    __syncthreads();

    // ---- L2 compute (accs in regs; two half-K passes) ----
    f32x4 acc2[2];
#pragma unroll
    for (int rt = 0; rt < 2; ++rt) acc2[rt] = (f32x4){0.f, 0.f, 0.f, 0.f};
    {
      const int col = wave * 16 + m16;
#pragma unroll
      for (int kh = 0; kh < 2; ++kh) {
        bf16x8 bh0 = *(const bf16x8*)(w2h + (col << 7) + ((quad + kh * 8) << 3));
        bf16x8 bl0 = *(const bf16x8*)(w2l + (col << 7) + ((quad + kh * 8) << 3));
        bf16x8 bh1 = *(const bf16x8*)(w2h + (col << 7) + ((quad + kh * 8 + 4) << 3));
        bf16x8 bl1 = *(const bf16x8*)(w2l + (col << 7) + ((quad + kh * 8 + 4) << 3));
#pragma unroll
        for (int lrt = 0; lrt < 2; ++lrt) {
          if (lrt >= NT) break;
          const int lr = lrt * 16 + m16;
          int ach0 = ((quad + kh * 8) ^ (m16 & 7)) << 3;
          int ach1 = ((quad + kh * 8 + 4) ^ (m16 & 7)) << 3;
          bf16x8 aH = *(const bf16x8*)(mHdH + (lr << 7) + ach0);
          bf16x8 aL = *(const bf16x8*)(mHdL + (lr << 7) + ach0);
          MFMA3(acc2[lrt], aH, aL, bh0, bl0)
          aH = *(const bf16x8*)(mHdH + (lr << 7) + ach1);
          aL = *(const bf16x8*)(mHdL + (lr << 7) + ach1);
          MFMA3(acc2[lrt], aH, aL, bh1, bl1)
        }
      }
    }
    __syncthreads();

    // ---- L2 writeback (relu -> mHd in place) ----
    {
      const int col = wave * 16 + m16;
      const float bias = b2v[col];
#pragma unroll
      for (int lrt = 0; lrt < 2; ++lrt) {
        if (lrt >= NT) break;
#pragma unroll
        for (int r = 0; r < 4; ++r) {
          float v = acc2[lrt][r] + bias; v = v > 0.f ? v : 0.f;
          int idx = SWZ7(lrt * 16 + quad * 4 + r, col);
          split2(v, mHdH[idx], mHdL[idx]);
        }
      }
    }
    __syncthreads();

    // ---- L3: mHd @ W3^T + b3 -> xc (skip col 50 and cols >= 56) ----
    {
      const int colt = wave & 3, rh = wave >> 2;
      const int col = colt * 16 + m16;     // 0..63
      const float bias = (col < 50) ? b3v[col] : 0.f;
      for (int lrt = rh; lrt < NT; lrt += 2) {
        const int lr = lrt * 16 + m16;
        f32x4 acc = (f32x4){0.f, 0.f, 0.f, 0.f};
#pragma unroll
        for (int kh = 0; kh < 2; ++kh) {
          bf16x8 bh0 = *(const bf16x8*)(w3h + (col << 7) + ((quad + kh * 8) << 3));
          bf16x8 bl0 = *(const bf16x8*)(w3l + (col << 7) + ((quad + kh * 8) << 3));
          bf16x8 bh1 = *(const bf16x8*)(w3h + (col << 7) + ((quad + kh * 8 + 4) << 3));
          bf16x8 bl1 = *(const bf16x8*)(w3l + (col << 7) + ((quad + kh * 8 + 4) << 3));
          int ach0 = ((quad + kh * 8) ^ (m16 & 7)) << 3;
          int ach1 = ((quad + kh * 8 + 4) ^ (m16 & 7)) << 3;
          bf16x8 aH = *(const bf16x8*)(mHdH + (lr << 7) + ach0);
          bf16x8 aL = *(const bf16x8*)(mHdL + (lr << 7) + ach0);
          MFMA3(acc, aH, aL, bh0, bl0)
          aH = *(const bf16x8*)(mHdH + (lr << 7) + ach1);
          aL = *(const bf16x8*)(mHdL + (lr << 7) + ach1);
          MFMA3(acc, aH, aL, bh1, bl1)
        }
        if (col != 50 && col < 56) {
#pragma unroll
          for (int r = 0; r < 4; ++r) {
            int grow = C0 + lrt * 16 + quad * 4 + r;
            int idx = SWZ6(grow, col);
            split2(acc[r] + bias, xcH[idx], xcL[idx]);
          }
        }
      }
      if (ck == 0 && t < 80) {            // col 50: y for rows<64, 0 for 64-79
        float v = (t < 64) ? data[(b * 80 + t) * 6 + 5] : 0.f;
        int idx = SWZ6(t, 50);
        split2(v, xcH[idx], xcL[idx]);
      }
    }
    __syncthreads();
  }
  // xc complete; b2 (mHd) dead.

  // =========================================================================
  // GAT phase. Weights/An from global (TLP hides latency at 4-resident);
  // single ping-pong buffer b2. Zero-frag trick for xc block 7.
  // =========================================================================
  f32x4 accA[2];

  // ---- GEMM1: T1 = sg1(xc rows 0-63) @ W1a^T ----
#pragma unroll
  for (int n = 0; n < 2; ++n) accA[n] = (f32x4){0.f, 0.f, 0.f, 0.f};
#pragma unroll
  for (int kb8 = 0; kb8 < 8; kb8 += 4) {
    int ach = ((quad + kb8) ^ (m16 & 7)) << 3;
    int k0 = (quad + kb8) << 3;
    bf16x8 aH, aL;
    if (kb8 == 4 && quad == 3) { aH = z8; aL = z8; }
    else {
      aH = *(const bf16x8*)(xcH + (arow << 6) + ach);
      aL = *(const bf16x8*)(xcL + (arow << 6) + ach);
    }
#pragma unroll
    for (int n = 0; n < 2; ++n) {
      const int col = (half * 2 + n) * 16 + m16;
      bf16x8 bH = *(const bf16x8*)(gaH + (col << 6) + k0);
      bf16x8 bL = *(const bf16x8*)(gaL + (col << 6) + k0);
      MFMA3(accA[n], aH, aL, bH, bL)
    }
  }
  // E1: T1 -> b2 [col][k]
  {
    const int kb = row0 + quad * 4;
#pragma unroll
    for (int n = 0; n < 2; ++n) {
      const int col = (half * 2 + n) * 16 + m16;
      int idx = (col << 6) + (((((kb >> 3) ^ (col & 7)) << 3)) | (kb & 7));
      s16x4 hv, lv;
#pragma unroll
      for (int r = 0; r < 4; ++r) {
        unsigned short hh, ll; split2(accA[n][r], hh, ll);
        hv[r] = (short)hh; lv[r] = (short)ll;
      }
      *(s16x4*)(b2H + idx) = hv; *(s16x4*)(b2L + idx) = lv;
    }
  }
  __syncthreads();   // S9

  // ---- GEMM2: P = relu(An @ T1) ----
#pragma unroll
  for (int n = 0; n < 2; ++n) accA[n] = (f32x4){0.f, 0.f, 0.f, 0.f};
#pragma unroll
  for (int kb8 = 0; kb8 < 8; kb8 += 4) {
    int ach = ((quad + kb8) ^ (m16 & 7)) << 3;
    int k0 = (quad + kb8) << 3;
    bf16x8 aH = *(const bf16x8*)(gAnH + (arow << 6) + k0);
    bf16x8 aL = *(const bf16x8*)(gAnL + (arow << 6) + k0);
#pragma unroll
    for (int n = 0; n < 2; ++n) {
      const int col = (half * 2 + n) * 16 + m16;
      int boff = (col << 6) + ach;
      bf16x8 bH = *(const bf16x8*)(b2H + boff);
      bf16x8 bL = *(const bf16x8*)(b2L + boff);
      MFMA3(accA[n], aH, aL, bH, bL)
    }
  }
  __syncthreads();   // S10 (b2 reads done)

  // E2: P -> b2
  {
    const int kb = row0 + quad * 4;
#pragma unroll
    for (int n = 0; n < 2; ++n) {
      const int col = (half * 2 + n) * 16 + m16;
      int idx = (col << 6) + (((((kb >> 3) ^ (col & 7)) << 3)) | (kb & 7));
      s16x4 hv, lv;
#pragma unroll
      for (int r = 0; r < 4; ++r) {
        float v = accA[n][r]; v = v > 0.f ? v : 0.f;
        unsigned short hh, ll; split2(v, hh, ll);
        hv[r] = (short)hh; lv[r] = (short)ll;
      }
      *(s16x4*)(b2H + idx) = hv; *(s16x4*)(b2L + idx) = lv;
    }
  }
  __syncthreads();   // S11

  // ---- GEMM3: Q = An @ P ----
#pragma unroll
  for (int n = 0; n < 2; ++n) accA[n] = (f32x4){0.f, 0.f, 0.f, 0.f};
#pragma unroll
  for (int kb8 = 0; kb8 < 8; kb8 += 4) {
    int ach = ((quad + kb8) ^ (m16 & 7)) << 3;
    int k0 = (quad + kb8) << 3;
    bf16x8 aH = *(const bf16x8*)(gAnH + (arow << 6) + k0);
    bf16x8 aL = *(const bf16x8*)(gAnL + (arow << 6) + k0);
#pragma unroll
    for (int n = 0; n < 2; ++n) {
      const int col = (half * 2 + n) * 16 + m16;
      int boff = (col << 6) + ach;
      bf16x8 bH = *(const bf16x8*)(b2H + boff);
      bf16x8 bL = *(const bf16x8*)(b2L + boff);
      MFMA3(accA[n], aH, aL, bH, bL)
    }
  }
  __syncthreads();   // S12 (b2 reads done)

  // E3: Q -> b2 [row][k]
#pragma unroll
  for (int n = 0; n < 2; ++n) {
    const int col = (half * 2 + n) * 16 + m16;
#pragma unroll
    for (int r = 0; r < 4; ++r) {
      int idx = SWZ6(row0 + quad * 4 + r, col);
      split2(accA[n][r], b2H[idx], b2L[idx]);
    }
  }
  __syncthreads();   // S13

  // ---- GEMM4: x1 = Q @ W1b^T ----
#pragma unroll
  for (int n = 0; n < 2; ++n) accA[n] = (f32x4){0.f, 0.f, 0.f, 0.f};
#pragma unroll
  for (int kb8 = 0; kb8 < 8; kb8 += 4) {
    int ach = ((quad + kb8) ^ (m16 & 7)) << 3;
    int k0 = (quad + kb8) << 3;
    bf16x8 aH = *(const bf16x8*)(b2H + (arow << 6) + ach);
    bf16x8 aL = *(const bf16x8*)(b2L + (arow << 6) + ach);
#pragma unroll
    for (int n = 0; n < 2; ++n) {
      const int col = (half * 2 + n) * 16 + m16;
      bf16x8 bH = *(const bf16x8*)(gbH + (col << 6) + k0);
      bf16x8 bL = *(const bf16x8*)(gbL + (col << 6) + k0);
      MFMA3(accA[n], aH, aL, bH, bL)
    }
  }
  __syncthreads();   // S14 (b2 reads done)

  // E4: x1 -> b2 [row][k]
#pragma unroll
  for (int n = 0; n < 2; ++n) {
    const int col = (half * 2 + n) * 16 + m16;
#pragma unroll
    for (int r = 0; r < 4; ++r) {
      int idx = SWZ6(row0 + quad * 4 + r, col);
      split2(accA[n][r], b2H[idx], b2L[idx]);
    }
  }
  __syncthreads();   // S15

  // ---- GEMM5: Zp = x1 @ WkT (4-term); half0 also Zf = xc[64:80] @ WkT ----
#pragma unroll
  for (int n = 0; n < 2; ++n) accA[n] = (f32x4){0.f, 0.f, 0.f, 0.f};
  f32x4 af = (f32x4){0.f, 0.f, 0.f, 0.f};
#pragma unroll
  for (int kb8 = 0; kb8 < 8; kb8 += 4) {
    int ach = ((quad + kb8) ^ (m16 & 7)) << 3;
    int k0 = (quad + kb8) << 3;
    bf16x8 aH = *(const bf16x8*)(b2H + (arow << 6) + ach);
    bf16x8 aL = *(const bf16x8*)(b2L + (arow << 6) + ach);
#pragma unroll
    for (int n = 0; n < 2; ++n) {
      const int col = (half * 2 + n) * 16 + m16;
      bf16x8 bH = *(const bf16x8*)(gwkH + (col << 6) + k0);
      bf16x8 bL = *(const bf16x8*)(gwkL + (col << 6) + k0);
      MFMA4(accA[n], aH, aL, bH, bL)
    }
  }
  if (half == 0) {
#pragma unroll
    for (int kb8 = 0; kb8 < 8; kb8 += 4) {
      int ach = ((quad + kb8) ^ (m16 & 7)) << 3;
      int k0 = (quad + kb8) << 3;
      bf16x8 aH, aL;
      if (kb8 == 4 && quad == 3) { aH = z8; aL = z8; }
      else {
        aH = *(const bf16x8*)(xcH + ((64 + m16) << 6) + ach);
        aL = *(const bf16x8*)(xcL + ((64 + m16) << 6) + ach);
      }
      const int col = s * 16 + m16;
      bf16x8 bH = *(const bf16x8*)(gwkH + (col << 6) + k0);
      bf16x8 bL = *(const bf16x8*)(gwkL + (col << 6) + k0);
      MFMA4(af, aH, aL, bH, bL)
    }
  }
  float s2r[4];
#pragma unroll
  for (int r = 0; r < 4; ++r)
    s2r[r] = accA[0][r] * accA[0][r] + accA[1][r] * accA[1][r];
#pragma unroll
  for (int m = 1; m < 16; m <<= 1)
#pragma unroll
    for (int r = 0; r < 4; ++r) s2r[r] += __shfl_xor(s2r[r], m);
  __syncthreads();   // S16 (b2 x1 reads done)

  // E5: Zp -> b2 [row][k]; zf (half0); spH2 -> xc slots (m16==0)
#pragma unroll
  for (int n = 0; n < 2; ++n) {
    const int h = (half * 2 + n) * 16 + m16;
#pragma unroll
    for (int r = 0; r < 4; ++r) {
      int idx = SWZ6(row0 + quad * 4 + r, h);
      split2(accA[n][r], b2H[idx], b2L[idx]);
    }
  }
  if (half == 0) {
    const int h = s * 16 + m16;
#pragma unroll
    for (int r = 0; r < 4; ++r) {
      int idx = SWZ6(quad * 4 + r, h);
      split2(af[r], zfH[idx], zfL[idx]);
    }
  }
  if (m16 == 0) {
#pragma unroll
    for (int r = 0; r < 4; ++r)
      SPH2(row0 + quad * 4 + r)[half] = s2r[r];
  }
  __syncthreads();   // S17

  // ---- GEMM6 (half0): cross = Zp @ Zf^T || sfS (half1) ----
  f32x4 ac2 = (f32x4){0.f, 0.f, 0.f, 0.f};
  if (half == 0) {
#pragma unroll
    for (int kb8 = 0; kb8 < 8; kb8 += 4) {
      int ach = ((quad + kb8) ^ (m16 & 7)) << 3;
      bf16x8 aH = *(const bf16x8*)(b2H + (arow << 6) + ach);
      bf16x8 aL = *(const bf16x8*)(b2L + (arow << 6) + ach);
      bf16x8 bH = *(const bf16x8*)(zfH + (m16 << 6) + ach);
      bf16x8 bL = *(const bf16x8*)(zfL + (m16 << 6) + ach);
      MFMA4(ac2, aH, aL, bH, bL)
    }
  } else {
    int idx = t - 256;
    int j = idx >> 4, h0 = (idx & 15) << 2;
    float p = 0.f;
#pragma unroll
    for (int r = 0; r < 4; ++r) {
      int ii = SWZ6(j, h0 + r);
      float v = bf2f(zfH[ii]) + bf2f(zfL[ii]);
      p += v * v;
    }
#pragma unroll
    for (int m = 1; m < 16; m <<= 1) p += __shfl_xor(p, m);
    if ((idx & 15) == 0) MS16(j)[0] = p;
  }
  __syncthreads();   // S18 (Zp reads done; b2 -> alS)

  // ---- alS write (b2 alias) ----
  if (half == 0) {
#pragma unroll
    for (int r = 0; r < 4; ++r) {
      int i = row0 + quad * 4 + r;
      alS[i * 17 + m16] = sc * ((SPH2(i)[0] + SPH2(i)[1]) + MS16(m16)[0] - 2.f * ac2[r]);
    }
  }
  __syncthreads();   // S19

  // ---- masked softmax over j per i ----
  if (t < 64) {
    const int i = t;
    float lv[16];
    float m = -3.4e38f;
#pragma unroll
    for (int j = 0; j < 16; ++j) {
      float v = (mk[j * 64 + i] != 0.f) ? alS[i * 17 + j] : NEGBIG;
      lv[j] = v;
      m = fmaxf(m, v);
    }
    float ssum = 0.f;
#pragma unroll
    for (int j = 0; j < 16; ++j) { lv[j] = expf(lv[j] - m); ssum += lv[j]; }
    float inv = 1.f / ssum;
#pragma unroll
    for (int j = 0; j < 16; ++j) alS[i * 17 + j] = lv[j] * inv;
  }
  __syncthreads();   // S20

  // ---- yh: 16 j x 16 lanes, 4 i each; yv from xc col 50 ----
  if (t < 256) {
    int j = t >> 4, i0 = (t & 15) << 2;
    float p = 0.f;
#pragma unroll
    for (int r = 0; r < 4; ++r) {
      int i = i0 + r;
      int iy = SWZ6(i, 50);
      float yv = bf2f(xcH[iy]) + bf2f(xcL[iy]);
      p += alS[i * 17 + j] * yv;
    }
#pragma unroll
    for (int m = 1; m < 16; m <<= 1) p += __shfl_xor(p, m);
    if ((t & 15) == 0) MS16(j)[1] = p;
  }
  __syncthreads();   // S21 (alS dead)

  // ---- xc col50 fixup (rows 64-79 <- yh); X2v/A22v/wb2 staging (b2 alias) ----
  if (t < 16) {
    int idx = SWZ6(64 + t, 50);
    split2(MS16(t)[1], xcH[idx], xcL[idx]);
  }
  for (int e = t; e < 832; e += 512) {
    int r = e / 52, c = e - r * 52;
    float v = 0.f;
    if (c < 50) {
      int i6 = SWZ6(64 + r, c);
      v = bf2f(xcH[i6]) + bf2f(xcL[i6]);
    } else if (c == 50) v = MS16(r)[1];
    X2v[e] = v;
  }
  for (int e = t; e < 256; e += 512) A22v[e] = an22[e];
  if (t < 64) wb2[t] = wg2b[t];
  __syncthreads();   // S22

  // ---- Phase A: diag Gram tiles -> sqS (waves 0-4) || G2v (waves 5-7) ----
  if (wave < 5) {
    const int ts = wave;
    f32x4 acc = (f32x4){0.f, 0.f, 0.f, 0.f};
#pragma unroll
    for (int kb8 = 0; kb8 < 8; kb8 += 4) {
      int ach = ((quad + kb8) ^ (m16 & 7)) << 3;
      bf16x8 aH, aL;
      if (kb8 == 4 && quad == 3) { aH = z8; aL = z8; }
      else {
        aH = *(const bf16x8*)(xcH + ((ts * 16 + m16) << 6) + ach);
        aL = *(const bf16x8*)(xcL + ((ts * 16 + m16) << 6) + ach);
      }
      MFMA3(acc, aH, aL, aH, aL)
    }
    if ((m16 >> 2) == quad) sqS[ts * 16 + m16] = acc[m16 & 3];
  } else {
    for (int e = t - 320; e < 1024; e += 192) {
      int j = e >> 6, h = e & 63;
      float ssum = 0.f;
      for (int k = 0; k < 51; ++k) ssum += X2v[j * 52 + k] * g2at[k * 64 + h];
      G2v[e] = ssum;
    }
  }
  __syncthreads();   // S23 (sqS + G2v visible)

  // ---- Phase B: all 25 Gram tiles, epilogue+store inline; Pmv ----
  {
    float* dist = out + OUT_DIST + b * 6400;
    for (int idx = wave; idx < 25; idx += 8) {
      int ts = idx / 5, tf = idx - ts * 5;
      f32x4 acc = (f32x4){0.f, 0.f, 0.f, 0.f};
#pragma unroll
      for (int kb8 = 0; kb8 < 8; kb8 += 4) {
        int ach = ((quad + kb8) ^ (m16 & 7)) << 3;
        bf16x8 aH, aL, bH, bL;
        if (kb8 == 4 && quad == 3) { aH = z8; aL = z8; bH = z8; bL = z8; }
        else {
          aH = *(const bf16x8*)(xcH + ((ts * 16 + m16) << 6) + ach);
          aL = *(const bf16x8*)(xcL + ((ts * 16 + m16) << 6) + ach);
          const int col = tf * 16 + m16;
          bH = *(const bf16x8*)(xcH + (col << 6) + ach);
          bL = *(const bf16x8*)(xcL + (col << 6) + ach);
        }
        MFMA3(acc, aH, aL, bH, bL)
      }
#pragma unroll
      for (int r = 0; r < 4; ++r) {
        int i = ts * 16 + quad * 4 + r;
        int m = tf * 16 + m16;
        float d2 = sqS[i] + sqS[m] - 2.f * acc[r];
        d2 = d2 > 0.f ? d2 : 0.f;
        dist[i * 80 + m] = d2 > 0.f ? sqrtf(d2) : 0.f;
      }
    }
  }
  for (int e = t; e < 1024; e += 512) {
    int j = e >> 6, h = e & 63;
    float ssum = 0.f;
#pragma unroll
    for (int k = 0; k < 16; ++k) ssum += A22v[j * 16 + k] * G2v[k * 64 + h];
    Pmv[e] = ssum > 0.f ? ssum : 0.f;
  }
  __syncthreads();   // S24
  if (t < 256) {
    int j = t >> 4, h0 = (t & 15) << 2;
    float p = 0.f;
#pragma unroll
    for (int r = 0; r < 4; ++r) p += Pmv[j * 64 + h0 + r] * wb2[h0 + r];
#pragma unroll
    for (int m = 1; m < 16; m <<= 1) p += __shfl_xor(p, m);
    if ((t & 15) == 0) zzv[j] = p;
  }
  __syncthreads();   // S25
  if (t < 16) {
    float ssum = 0.f;
#pragma unroll
    for (int k = 0; k < 16; ++k) ssum += A22v[t * 16 + k] * zzv[k];
    out[OUT_OUT + b * 16 + t] = ssum;
  }
}

// ===========================================================================
extern "C" void kernel_launch(void* const* d_in, const int* in_sizes, int n_in,
                              void* d_out, int out_size, void* d_ws, size_t ws_size,
                              hipStream_t stream)
{
  const float* data = (const float*)d_in[0];
  const float* emb0 = (const float*)d_in[1];
  const float* emb1 = (const float*)d_in[2];
  const float* emb2 = (const float*)d_in[3];
  const float* w1   = (const float*)d_in[4];
  const float* b1   = (const float*)d_in[5];
  const float* w2   = (const float*)d_in[6];
  const float* b2   = (const float*)d_in[7];
  const float* w3   = (const float*)d_in[8];
  const float* b3   = (const float*)d_in[9];
  const float* M    = (const float*)d_in[10];
  const float* wg1a = (const float*)d_in[11];
  const float* wg1b = (const float*)d_in[12];
  const float* Wk   = (const float*)d_in[13];
  const float* smo  = (const float*)d_in[14];
  const float* wg2a = (const float*)d_in[15];
  const float* wg2b = (const float*)d_in[16];
  float* ws  = (float*)d_ws;
  float* out = (float*)d_out;

  k_prep <<<dim3(4),    dim3(256), 0, stream>>>(M, Wk, smo, w1, w2, w3, wg1a, wg1b, wg2a, ws, out);
  k_fused<<<dim3(1024), dim3(512), 0, stream>>>(data, emb0, emb1, emb2, b1, b2, b3, wg2b, ws, out);
}

// Round 10
// 198.386 us; speedup vs baseline: 1.3698x; 1.2324x over previous
//
#include <hip/hip_runtime.h>
#include <math.h>

// ---------------------------------------------------------------------------
// GAT_23613730193923 — round 19: revert to round 10 (best verified: 92us
// k_fused / 200.3us total; 80KB LDS, weights staged in LDS) + 2 micro-opts:
//  - An A-frags hoisted to regs across GEMM2+GEMM3 (same LDS addrs in both):
//    removes 16 ds_read_b128/wave, reg->MFMA after barriers. +16 VGPR, safe
//    (occupancy LDS-capped at 2 blocks: 81920*2 = 160KB exactly).
//  - spS fold: spH2[2i]+spH2[2i+1] read directly in alS write (bitwise same).
// Occupancy campaign closed: reg tier (VGPR+AGPR unified) caps at 2 blk/CU
// without spill (r17/r18 evidence); precision split is load-bearing (sc~-100
// amplifies q errors into softmax).
// ---------------------------------------------------------------------------

#define NEGBIG (-1e30f)

// ---- workspace offsets (floats) ----
#define OFF_X     0          // (unused; layout compat)
#define OFF_A     7471104    // 80*80
#define OFF_AN22  7481600    // 16*16
#define OFF_MK    7484356    // 16*64
#define OFF_GAH   7514692    // W1a hi: 64*64 ushort
#define OFF_GAL   7516740
#define OFF_G2AT  7521156    // 51*64 fp32
#define OFF_SC    7524420    // 1
#define OFF_W1H   7524424    // 128*64 ushort
#define OFF_W1L   7528520
#define OFF_W2H   7532616    // 128*128 ushort
#define OFF_W2L   7540808
#define OFF_W3H   7549000    // 64*128 ushort
#define OFF_W3L   7553096
#define OFF_ANH   7557192    // An11 hi: 64*64 ushort
#define OFF_ANL   7559240
#define OFF_GBH   7561288    // W1b hi: 64*64 ushort
#define OFF_GBL   7563336
#define OFF_WKH   7565384    // Wk^T hi: [h=64][o=64] ushort
#define OFF_WKL   7567432

// ---- output offsets (floats): (out B*16, dist B*6400, A 6400) ----
#define OUT_OUT   0
#define OUT_DIST  16384
#define OUT_A     6569984

typedef __attribute__((ext_vector_type(8))) short bf16x8;
typedef __attribute__((ext_vector_type(4))) short s16x4;
typedef __attribute__((ext_vector_type(4))) float f32x4;

__device__ __forceinline__ unsigned short f2bf(float x) {  // RTN
  union { float f; unsigned u; } v; v.f = x;
  unsigned r = v.u + 0x7fffu + ((v.u >> 16) & 1u);
  return (unsigned short)(r >> 16);
}
__device__ __forceinline__ float bf2f(unsigned short h) {
  union { unsigned u; float f; } v; v.u = ((unsigned)h) << 16; return v.f;
}
__device__ __forceinline__ void split2(float v, unsigned short& h, unsigned short& l) {
  unsigned short hh = f2bf(v);
  h = hh;
  l = f2bf(v - bf2f(hh));
}
#define SWZ6(r, k) (((r) << 6) + (((((k) >> 3) ^ ((r) & 7)) << 3) | ((k) & 7)))
#define SWZ7(r, k) (((r) << 7) + (((((k) >> 3) ^ ((r) & 7)) << 3) | ((k) & 7)))

#define MFMA3(acc, aH, aL, bH, bL) \
  acc = __builtin_amdgcn_mfma_f32_16x16x32_bf16(aH, bH, acc, 0, 0, 0); \
  acc = __builtin_amdgcn_mfma_f32_16x16x32_bf16(aH, bL, acc, 0, 0, 0); \
  acc = __builtin_amdgcn_mfma_f32_16x16x32_bf16(aL, bH, acc, 0, 0, 0);
#define MFMA4(acc, aH, aL, bH, bL) \
  MFMA3(acc, aH, aL, bH, bL) \
  acc = __builtin_amdgcn_mfma_f32_16x16x32_bf16(aL, bL, acc, 0, 0, 0);

// ===========================================================================
// k_prep (unchanged)
// ===========================================================================
__global__ __launch_bounds__(256) void k_prep(
    const float* __restrict__ M, const float* __restrict__ Wk,
    const float* __restrict__ sm,
    const float* __restrict__ w1, const float* __restrict__ w2,
    const float* __restrict__ w3,
    const float* __restrict__ wg1a, const float* __restrict__ wg1b,
    const float* __restrict__ wg2a,
    float* __restrict__ ws, float* __restrict__ out)
{
  __shared__ float Msh[80 * 26];
  __shared__ float Ash[80 * 80];
  __shared__ float d1[64];
  __shared__ float d2s[16];
  const int t = threadIdx.x;

  if (blockIdx.x == 0) {
    for (int e = t; e < 80 * 26; e += 256) Msh[e] = M[e];
    __syncthreads();
    for (int e = t; e < 6400; e += 256) {
      int i = e / 80, j = e % 80;
      float v = 0.f;
      if (j < i) {
        float s = 0.f;
        for (int k = 0; k < 26; ++k) s += Msh[i * 26 + k] * Msh[j * 26 + k];
        v = s > 0.f ? s : 0.f;
      }
      Ash[e] = v;
    }
    __syncthreads();
    if (t > 0 && t < 80) {
      int i = t;
      float m = -3.4e38f;
      for (int j = 0; j < i; ++j) m = fmaxf(m, Ash[i * 80 + j]);
      float s = 0.f;
      for (int j = 0; j < i; ++j) {
        float e = expf(Ash[i * 80 + j] - m);
        Ash[i * 80 + j] = e;
        s += e;
      }
      float inv = 1.f / s;
      for (int j = 0; j < i; ++j) Ash[i * 80 + j] *= inv;
    }
    __syncthreads();
    {
      float* Aws = ws + OFF_A;
      float* Aout = out + OUT_A;
      for (int e = t; e < 6400; e += 256) { Aws[e] = Ash[e]; Aout[e] = Ash[e]; }
    }
    if (t < 64) {
      int c = 0;
      for (int j = 0; j < 64; ++j) if (Ash[t * 80 + j] > 1e-15f) ++c;
      d1[t] = 1.f / sqrtf(1.f + (float)c);
    } else if (t < 80) {
      int i = t - 64; int c = 0;
      for (int j = 0; j < 16; ++j) if (Ash[(64 + i) * 80 + 64 + j] > 1e-15f) ++c;
      d2s[i] = 1.f / sqrtf(1.f + (float)c);
    }
    __syncthreads();
    {
      float* an22 = ws + OFF_AN22;
      unsigned short* anH = (unsigned short*)(ws + OFF_ANH);
      unsigned short* anL = (unsigned short*)(ws + OFF_ANL);
      for (int e = t; e < 4096; e += 256) {
        int i = e >> 6, j = e & 63;
        float v = d1[i] * Ash[i * 80 + j] * d1[j];
        unsigned short h = f2bf(v);
        anH[e] = h; anL[e] = f2bf(v - bf2f(h));
      }
      for (int e = t; e < 256; e += 256) {
        int i = e >> 4, j = e & 15;
        an22[e] = d2s[i] * Ash[(64 + i) * 80 + 64 + j] * d2s[j];
      }
    }
    if (t < 16) {
      float* mk = ws + OFF_MK;
      int j = t;
      float m = -3.4e38f;
      for (int i = 0; i < 64; ++i) {
        float v = Ash[(64 + j) * 80 + i];
        v = (v != 0.f) ? v : NEGBIG;
        m = fmaxf(m, v);
      }
      float s = 0.f;
      for (int i = 0; i < 64; ++i) {
        float v = Ash[(64 + j) * 80 + i];
        v = (v != 0.f) ? v : NEGBIG;
        s += expf(v - m);
      }
      float inv = 1.f / s;
      for (int i = 0; i < 64; ++i) {
        float v = Ash[(64 + j) * 80 + i];
        v = (v != 0.f) ? v : NEGBIG;
        mk[j * 64 + i] = (expf(v - m) * inv >= 0.004f) ? 1.f : 0.f;
      }
    }
  } else if (blockIdx.x == 1) {
    unsigned short* wkh = (unsigned short*)(ws + OFF_WKH);
    unsigned short* wkl = (unsigned short*)(ws + OFF_WKL);
    for (int e = t; e < 4096; e += 256) {
      int h = e >> 6, o = e & 63;
      float v = (o < 50) ? Wk[o * 64 + h] : 0.f;
      unsigned short hh = f2bf(v);
      wkh[e] = hh; wkl[e] = f2bf(v - bf2f(hh));
    }
    if (t == 0) {
      float v = sm[0];
      float sig = 1.f / (1.f + expf(-v));
      (ws + OFF_SC)[0] = -0.5f / (sig * 0.01f);
    }
  } else if (blockIdx.x == 2) {
    unsigned short* w1h = (unsigned short*)(ws + OFF_W1H);
    unsigned short* w1l = (unsigned short*)(ws + OFF_W1L);
    for (int e = t; e < 8192; e += 256) {
      int n = e >> 6, k = e & 63;
      float v = (k < 51) ? w1[n * 51 + k] : 0.f;
      unsigned short h = f2bf(v);
      w1h[e] = h; w1l[e] = f2bf(v - bf2f(h));
    }
    unsigned short* w3h = (unsigned short*)(ws + OFF_W3H);
    unsigned short* w3l = (unsigned short*)(ws + OFF_W3L);
    for (int e = t; e < 8192; e += 256) {
      int n = e >> 7, k = e & 127;
      float v = (n < 50) ? w3[n * 128 + k] : 0.f;
      unsigned short h = f2bf(v);
      w3h[e] = h; w3l[e] = f2bf(v - bf2f(h));
    }
    unsigned short* gah = (unsigned short*)(ws + OFF_GAH);
    unsigned short* gal = (unsigned short*)(ws + OFF_GAL);
    for (int e = t; e < 4096; e += 256) {
      int n = e >> 6, k = e & 63;
      float v = (k < 51) ? wg1a[n * 51 + k] : 0.f;
      unsigned short h = f2bf(v);
      gah[e] = h; gal[e] = f2bf(v - bf2f(h));
    }
  } else {
    unsigned short* w2h = (unsigned short*)(ws + OFF_W2H);
    unsigned short* w2l = (unsigned short*)(ws + OFF_W2L);
    for (int e = t; e < 16384; e += 256) {
      int n = e >> 7, k = e & 127;
      float v = w2[n * 128 + k];
      unsigned short h = f2bf(v);
      w2h[e] = h; w2l[e] = f2bf(v - bf2f(h));
    }
    unsigned short* gbh = (unsigned short*)(ws + OFF_GBH);
    unsigned short* gbl = (unsigned short*)(ws + OFF_GBL);
    for (int e = t; e < 4096; e += 256) {
      int n = e >> 6, k = e & 63;
      float v = (n < 50) ? wg1b[n * 64 + k] : 0.f;
      unsigned short h = f2bf(v);
      gbh[e] = h; gbl[e] = f2bf(v - bf2f(h));
    }
    float* g2at = ws + OFF_G2AT;
    for (int e = t; e < 64 * 51; e += 256) { int o = e / 51, k = e % 51; g2at[k * 64 + o] = wg2a[e]; }
  }
}

// ===========================================================================
// k_fused: per-batch MLP (80 rows) + g1 + q + g2 + dist.
// 512 threads, 1 batch/block, 64KB SH + 16KB xbuf = 80KB LDS (2 blocks/CU).
// Round-10 structure; An-frags reg-hoisted for GEMM2/3; spS folded.
// ===========================================================================
__global__ __launch_bounds__(512, 4) void k_fused(
    const float* __restrict__ data,
    const float* __restrict__ emb0, const float* __restrict__ emb1,
    const float* __restrict__ emb2,
    const float* __restrict__ b1v, const float* __restrict__ b2v,
    const float* __restrict__ b3v,
    const float* __restrict__ wg2b,
    float* __restrict__ ws, float* __restrict__ out)
{
  __shared__ __align__(16) unsigned short SH[32768];
  __shared__ __align__(16) float xbuf[80 * 51];

  const int t = threadIdx.x, b = blockIdx.x;
  const int lane = t & 63, wave = t >> 6;
  const int m16 = lane & 15, quad = lane >> 4;

  // =========================================================================
  // MLP phase
  // =========================================================================
  {
    unsigned short* mIaH = SH;            // 80*64
    unsigned short* mIaL = SH + 5120;
    unsigned short* mHdH = SH + 10240;    // 80*128
    unsigned short* mHdL = SH + 20480;
    const unsigned short* w1h = (const unsigned short*)(ws + OFF_W1H);
    const unsigned short* w1l = (const unsigned short*)(ws + OFF_W1L);
    const unsigned short* w2h = (const unsigned short*)(ws + OFF_W2H);
    const unsigned short* w2l = (const unsigned short*)(ws + OFF_W2L);
    const unsigned short* w3h = (const unsigned short*)(ws + OFF_W3H);
    const unsigned short* w3l = (const unsigned short*)(ws + OFF_W3L);

    // ---- embed gather -> mIa (swz6); data col5 -> xbuf col 50 ----
    for (int e = t; e < 5120; e += 512) {
      int r = e >> 6, c = e & 63;
      int g = b * 80 + r;
      float v = 0.f;
      if (c < 32)      { int i0 = (int)data[g * 6 + 0]; v = emb0[i0 * 32 + c]; }
      else if (c < 40) { int i1 = (int)data[g * 6 + 1]; v = emb1[i1 * 8 + (c - 32)]; }
      else if (c < 48) { int i2 = (int)data[g * 6 + 2]; v = emb2[i2 * 8 + (c - 40)]; }
      else if (c < 51) { v = data[g * 6 + 3 + (c - 48)]; }
      int idx = SWZ6(r, c);
      split2(v, mIaH[idx], mIaL[idx]);
    }
    if (t < 80) xbuf[t * 51 + 50] = data[(b * 80 + t) * 6 + 5];
    __syncthreads();   // BM1

    // ---- L1: act(80x64) @ W1^T -> relu -> mHd (80x128) ----
    {
      const int col = wave * 16 + m16;     // 0..127, fixed per wave
      bf16x8 bH0 = *(const bf16x8*)(w1h + (col << 6) + (quad << 3));
      bf16x8 bL0 = *(const bf16x8*)(w1l + (col << 6) + (quad << 3));
      bf16x8 bH1 = *(const bf16x8*)(w1h + (col << 6) + ((quad + 4) << 3));
      bf16x8 bL1 = *(const bf16x8*)(w1l + (col << 6) + ((quad + 4) << 3));
      const float bias = b1v[col];
      const int ach0 = ((quad + 0) ^ (m16 & 7)) << 3;
      const int ach1 = ((quad + 4) ^ (m16 & 7)) << 3;
#pragma unroll
      for (int rt = 0; rt < 5; ++rt) {
        const int ar = rt * 16 + m16;
        f32x4 acc = (f32x4){0.f, 0.f, 0.f, 0.f};
        bf16x8 aH = *(const bf16x8*)(mIaH + (ar << 6) + ach0);
        bf16x8 aL = *(const bf16x8*)(mIaL + (ar << 6) + ach0);
        MFMA3(acc, aH, aL, bH0, bL0)
        aH = *(const bf16x8*)(mIaH + (ar << 6) + ach1);
        aL = *(const bf16x8*)(mIaL + (ar << 6) + ach1);
        MFMA3(acc, aH, aL, bH1, bL1)
#pragma unroll
        for (int r = 0; r < 4; ++r) {
          float v = acc[r] + bias; v = v > 0.f ? v : 0.f;
          int idx = SWZ7(rt * 16 + quad * 4 + r, col);
          split2(v, mHdH[idx], mHdL[idx]);
        }
      }
    }
    __syncthreads();   // BM2

    // ---- L2: mHd @ W2^T -> regs; barrier; relu -> mHd (in place) ----
    f32x4 acc2[5];
    {
      const int col = wave * 16 + m16;
      bf16x8 bh[4], bl[4];
#pragma unroll
      for (int kk = 0; kk < 4; ++kk) {
        bh[kk] = *(const bf16x8*)(w2h + (col << 7) + ((quad + kk * 4) << 3));
        bl[kk] = *(const bf16x8*)(w2l + (col << 7) + ((quad + kk * 4) << 3));
      }
#pragma unroll
      for (int rt = 0; rt < 5; ++rt) {
        const int ar = rt * 16 + m16;
        f32x4 acc = (f32x4){0.f, 0.f, 0.f, 0.f};
#pragma unroll
        for (int kk = 0; kk < 4; ++kk) {
          int ach = ((quad + kk * 4) ^ (m16 & 7)) << 3;
          bf16x8 aH = *(const bf16x8*)(mHdH + (ar << 7) + ach);
          bf16x8 aL = *(const bf16x8*)(mHdL + (ar << 7) + ach);
          MFMA3(acc, aH, aL, bh[kk], bl[kk])
        }
        acc2[rt] = acc;
      }
    }
    __syncthreads();   // BM3 (all reads of mHd done)
    {
      const int col = wave * 16 + m16;
      const float bias = b2v[col];
#pragma unroll
      for (int rt = 0; rt < 5; ++rt) {
#pragma unroll
        for (int r = 0; r < 4; ++r) {
          float v = acc2[rt][r] + bias; v = v > 0.f ? v : 0.f;
          int idx = SWZ7(rt * 16 + quad * 4 + r, col);
          split2(v, mHdH[idx], mHdL[idx]);
        }
      }
    }
    __syncthreads();   // BM4

    // ---- L3: mHd @ W3^T + b3 -> xbuf cols 0..49 ----
    {
      const int ct = wave & 3, rh = wave >> 2;
      const int col = ct * 16 + m16;       // 0..63 (50 used)
      bf16x8 bh[4], bl[4];
#pragma unroll
      for (int kk = 0; kk < 4; ++kk) {
        bh[kk] = *(const bf16x8*)(w3h + (col << 7) + ((quad + kk * 4) << 3));
        bl[kk] = *(const bf16x8*)(w3l + (col << 7) + ((quad + kk * 4) << 3));
      }
      const float bias = (col < 50) ? b3v[col] : 0.f;
      for (int rt = rh; rt < 5; rt += 2) {
        const int ar = rt * 16 + m16;
        f32x4 acc = (f32x4){0.f, 0.f, 0.f, 0.f};
#pragma unroll
        for (int kk = 0; kk < 4; ++kk) {
          int ach = ((quad + kk * 4) ^ (m16 & 7)) << 3;
          bf16x8 aH = *(const bf16x8*)(mHdH + (ar << 7) + ach);
          bf16x8 aL = *(const bf16x8*)(mHdL + (ar << 7) + ach);
          MFMA3(acc, aH, aL, bh[kk], bl[kk])
        }
        if (col < 50) {
#pragma unroll
          for (int r = 0; r < 4; ++r)
            xbuf[(rt * 16 + quad * 4 + r) * 51 + col] = acc[r] + bias;
        }
      }
    }
    __syncthreads();   // BM5 (xbuf complete; SH fully dead)
  }

  // =========================================================================
  // GAT phase (round-9 k_gqd body; x reads -> xbuf)
  // =========================================================================
  unsigned short* b1H = SH;
  unsigned short* b1L = SH + 4096;
  unsigned short* b2H = SH + 8192;
  unsigned short* b2L = SH + 12288;
  unsigned short* anH = SH + 16384;
  unsigned short* anL = SH + 20480;
  unsigned short* wH  = SH + 24576;
  unsigned short* wL  = SH + 28672;
  unsigned short* xfH = SH + 24576;
  unsigned short* xfL = SH + 25600;
  unsigned short* zfH = SH + 26624;
  unsigned short* zfL = SH + 27648;
  float* alS  = (float*)(SH + 28672);   // 64*17 fl
  float* spH2 = (float*)(SH + 30848);   // 128 fl
  float* sfS  = (float*)(SH + 31232);   // 16
  float* yvS  = (float*)(SH + 31264);   // 64
  float* yhsS = (float*)(SH + 31392);   // 16
  float* X2v  = (float*)(SH + 8192);    // 832 fl
  float* A22v = X2v + 832;              // 256
  float* G2v  = A22v + 256;             // 1024
  float* Pmv  = G2v + 1024;             // 1024
  float* wb2  = Pmv + 1024;             // 64
  float* zzv  = wb2 + 64;               // 16
  unsigned short* xcH = SH;             // 5120 u
  unsigned short* xcL = SH + 16384;     // 5120 u
  float* sqS = (float*)(SH + 21504);    // 80 fl

  const int s = wave & 3, half = wave >> 2;
  const int row0 = s * 16;
  const int arow = row0 + m16;
  const float* mk = ws + OFF_MK;
  const float* an22 = ws + OFF_AN22;
  const float* g2at = ws + OFF_G2AT;
  const unsigned short* gAnH = (const unsigned short*)(ws + OFF_ANH);
  const unsigned short* gAnL = (const unsigned short*)(ws + OFF_ANL);
  const unsigned short* gaH = (const unsigned short*)(ws + OFF_GAH);
  const unsigned short* gaL = (const unsigned short*)(ws + OFF_GAL);
  const unsigned short* gbH = (const unsigned short*)(ws + OFF_GBH);
  const unsigned short* gbL = (const unsigned short*)(ws + OFF_GBL);
  const unsigned short* gwkH = (const unsigned short*)(ws + OFF_WKH);
  const unsigned short* gwkL = (const unsigned short*)(ws + OFF_WKL);
  const float sc = (ws + OFF_SC)[0];

  // ---- P0: stage sg1, An, W1a; yv in reg; prefetch W1b ----
  for (int e = t; e < 4096; e += 512) {
    int r = e >> 6, k = e & 63;
    float v = (k < 51) ? xbuf[r * 51 + k] : 0.f;
    int idx = SWZ6(r, k);
    split2(v, b1H[idx], b1L[idx]);
  }
  {
    int q = t;
    if (q < 512) {
      int r = q >> 3, c = q & 7;
      int dst = (r << 6) + ((c ^ (r & 7)) << 3);
      int src = (r << 6) + (c << 3);
      *(bf16x8*)(anH + dst) = *(const bf16x8*)(gAnH + src);
      *(bf16x8*)(anL + dst) = *(const bf16x8*)(gAnL + src);
      *(bf16x8*)(wH + dst)  = *(const bf16x8*)(gaH + src);
      *(bf16x8*)(wL + dst)  = *(const bf16x8*)(gaL + src);
    }
  }
  float yvreg = 0.f;
  if (t < 64) yvreg = xbuf[t * 51 + 50];
  bf16x8 pH, pL;
  {
    int q = t & 511;
    int r = q >> 3, c = q & 7;
    int src = (r << 6) + (c << 3);
    pH = *(const bf16x8*)(gbH + src);
    pL = *(const bf16x8*)(gbL + src);
  }
  __syncthreads();   // B1

  // ---- GEMM1: T1 = sg1 @ W1a^T ----
  f32x4 accA[2];
#pragma unroll
  for (int n = 0; n < 2; ++n) accA[n] = (f32x4){0.f, 0.f, 0.f, 0.f};
#pragma unroll
  for (int kb8 = 0; kb8 < 8; kb8 += 4) {
    int ach = ((quad + kb8) ^ (m16 & 7)) << 3;
    bf16x8 aH = *(const bf16x8*)(b1H + (arow << 6) + ach);
    bf16x8 aL = *(const bf16x8*)(b1L + (arow << 6) + ach);
#pragma unroll
    for (int n = 0; n < 2; ++n) {
      const int col = (half * 2 + n) * 16 + m16;
      int boff = (col << 6) + ach;
      bf16x8 bH = *(const bf16x8*)(wH + boff);
      bf16x8 bL = *(const bf16x8*)(wL + boff);
      MFMA3(accA[n], aH, aL, bH, bL)
    }
  }
  __syncthreads();   // B2

  // ---- E1: T1 -> B2 [col][k]; W1b -> W; prefetch WkT ----
  {
    const int kb = row0 + quad * 4;
#pragma unroll
    for (int n = 0; n < 2; ++n) {
      const int col = (half * 2 + n) * 16 + m16;
      int idx = (col << 6) + (((((kb >> 3) ^ (col & 7)) << 3)) | (kb & 7));
      s16x4 hv, lv;
#pragma unroll
      for (int r = 0; r < 4; ++r) {
        unsigned short hh, ll; split2(accA[n][r], hh, ll);
        hv[r] = (short)hh; lv[r] = (short)ll;
      }
      *(s16x4*)(b2H + idx) = hv; *(s16x4*)(b2L + idx) = lv;
    }
  }
  {
    int q = t & 511;
    int r = q >> 3, c = q & 7;
    int dst = (r << 6) + ((c ^ (r & 7)) << 3);
    *(bf16x8*)(wH + dst) = pH;
    *(bf16x8*)(wL + dst) = pL;
    int src = (r << 6) + (c << 3);
    pH = *(const bf16x8*)(gwkH + src);
    pL = *(const bf16x8*)(gwkL + src);
  }
  __syncthreads();   // B3

  // ---- An A-frags hoisted to regs (reused by GEMM2 AND GEMM3) ----
  bf16x8 anAH[2], anAL[2];
#pragma unroll
  for (int kk = 0; kk < 2; ++kk) {
    int ach = ((quad + kk * 4) ^ (m16 & 7)) << 3;
    anAH[kk] = *(const bf16x8*)(anH + (arow << 6) + ach);
    anAL[kk] = *(const bf16x8*)(anL + (arow << 6) + ach);
  }

  // ---- GEMM2: P = relu(An @ T1) ----
#pragma unroll
  for (int n = 0; n < 2; ++n) accA[n] = (f32x4){0.f, 0.f, 0.f, 0.f};
#pragma unroll
  for (int kb8 = 0; kb8 < 8; kb8 += 4) {
    const int kk = kb8 >> 2;
    int ach = ((quad + kb8) ^ (m16 & 7)) << 3;
#pragma unroll
    for (int n = 0; n < 2; ++n) {
      const int col = (half * 2 + n) * 16 + m16;
      int boff = (col << 6) + ach;
      bf16x8 bH = *(const bf16x8*)(b2H + boff);
      bf16x8 bL = *(const bf16x8*)(b2L + boff);
      MFMA3(accA[n], anAH[kk], anAL[kk], bH, bL)
    }
  }
  __syncthreads();   // B4

  // ---- E2: P -> B2 ----
  {
    const int kb = row0 + quad * 4;
#pragma unroll
    for (int n = 0; n < 2; ++n) {
      const int col = (half * 2 + n) * 16 + m16;
      int idx = (col << 6) + (((((kb >> 3) ^ (col & 7)) << 3)) | (kb & 7));
      s16x4 hv, lv;
#pragma unroll
      for (int r = 0; r < 4; ++r) {
        float v = accA[n][r]; v = v > 0.f ? v : 0.f;
        unsigned short hh, ll; split2(v, hh, ll);
        hv[r] = (short)hh; lv[r] = (short)ll;
      }
      *(s16x4*)(b2H + idx) = hv; *(s16x4*)(b2L + idx) = lv;
    }
  }
  __syncthreads();   // B5

  // ---- GEMM3: Q = An @ P (An from regs) ----
#pragma unroll
  for (int n = 0; n < 2; ++n) accA[n] = (f32x4){0.f, 0.f, 0.f, 0.f};
#pragma unroll
  for (int kb8 = 0; kb8 < 8; kb8 += 4) {
    const int kk = kb8 >> 2;
    int ach = ((quad + kb8) ^ (m16 & 7)) << 3;
#pragma unroll
    for (int n = 0; n < 2; ++n) {
      const int col = (half * 2 + n) * 16 + m16;
      int boff = (col << 6) + ach;
      bf16x8 bH = *(const bf16x8*)(b2H + boff);
      bf16x8 bL = *(const bf16x8*)(b2L + boff);
      MFMA3(accA[n], anAH[kk], anAL[kk], bH, bL)
    }
  }
  __syncthreads();   // B6

  // ---- E3: Q -> B1 [row][k]; WkT -> AN ----
#pragma unroll
  for (int n = 0; n < 2; ++n) {
    const int col = (half * 2 + n) * 16 + m16;
#pragma unroll
    for (int r = 0; r < 4; ++r) {
      int idx = SWZ6(row0 + quad * 4 + r, col);
      split2(accA[n][r], b1H[idx], b1L[idx]);
    }
  }
  {
    int q = t & 511;
    int r = q >> 3, c = q & 7;
    int dst = (r << 6) + ((c ^ (r & 7)) << 3);
    *(bf16x8*)(anH + dst) = pH;
    *(bf16x8*)(anL + dst) = pL;
  }
  float xf0 = 0.f, xf1 = 0.f;
  {
    int e0 = t, e1 = t + 512;
    int r0r = e0 >> 6, c0 = e0 & 63;
    int r1r = e1 >> 6, c1 = e1 & 63;
    if (c0 < 50) xf0 = xbuf[(64 + r0r) * 51 + c0];
    if (c1 < 50) xf1 = xbuf[(64 + r1r) * 51 + c1];
  }
  __syncthreads();   // B7

  // ---- GEMM4: x1 = Q @ W1b^T ----
#pragma unroll
  for (int n = 0; n < 2; ++n) accA[n] = (f32x4){0.f, 0.f, 0.f, 0.f};
#pragma unroll
  for (int kb8 = 0; kb8 < 8; kb8 += 4) {
    int ach = ((quad + kb8) ^ (m16 & 7)) << 3;
    bf16x8 aH = *(const bf16x8*)(b1H + (arow << 6) + ach);
    bf16x8 aL = *(const bf16x8*)(b1L + (arow << 6) + ach);
#pragma unroll
    for (int n = 0; n < 2; ++n) {
      const int col = (half * 2 + n) * 16 + m16;
      int boff = (col << 6) + ach;
      bf16x8 bH = *(const bf16x8*)(wH + boff);
      bf16x8 bL = *(const bf16x8*)(wL + boff);
      MFMA3(accA[n], aH, aL, bH, bL)
    }
  }
  __syncthreads();   // B8

  // ---- E4: x1 -> B2 [row][k]; xf -> XF; yv -> yvS ----
#pragma unroll
  for (int n = 0; n < 2; ++n) {
    const int col = (half * 2 + n) * 16 + m16;
#pragma unroll
    for (int r = 0; r < 4; ++r) {
      int idx = SWZ6(row0 + quad * 4 + r, col);
      split2(accA[n][r], b2H[idx], b2L[idx]);
    }
  }
  {
    int e0 = t, e1 = t + 512;
    int i0 = SWZ6(e0 >> 6, e0 & 63);
    int i1 = SWZ6(e1 >> 6, e1 & 63);
    split2(xf0, xfH[i0], xfL[i0]);
    split2(xf1, xfH[i1], xfL[i1]);
  }
  if (t < 64) yvS[t] = yvreg;
  __syncthreads();   // B9

  // ---- GEMM5: Zp = x1 @ WkT (4-term); Zf on half0; sp via shuffles ----
#pragma unroll
  for (int n = 0; n < 2; ++n) accA[n] = (f32x4){0.f, 0.f, 0.f, 0.f};
#pragma unroll
  for (int kb8 = 0; kb8 < 8; kb8 += 4) {
    int ach = ((quad + kb8) ^ (m16 & 7)) << 3;
    bf16x8 aH = *(const bf16x8*)(b2H + (arow << 6) + ach);
    bf16x8 aL = *(const bf16x8*)(b2L + (arow << 6) + ach);
#pragma unroll
    for (int n = 0; n < 2; ++n) {
      const int col = (half * 2 + n) * 16 + m16;
      int boff = (col << 6) + ach;
      bf16x8 bH = *(const bf16x8*)(anH + boff);
      bf16x8 bL = *(const bf16x8*)(anL + boff);
      MFMA4(accA[n], aH, aL, bH, bL)
    }
  }
  if (half == 0) {
    f32x4 af = (f32x4){0.f, 0.f, 0.f, 0.f};
#pragma unroll
    for (int kb8 = 0; kb8 < 8; kb8 += 4) {
      int ach = ((quad + kb8) ^ (m16 & 7)) << 3;
      bf16x8 aH = *(const bf16x8*)(xfH + (m16 << 6) + ach);
      bf16x8 aL = *(const bf16x8*)(xfL + (m16 << 6) + ach);
      const int col = s * 16 + m16;
      int boff = (col << 6) + ach;
      bf16x8 bH = *(const bf16x8*)(anH + boff);
      bf16x8 bL = *(const bf16x8*)(anL + boff);
      MFMA4(af, aH, aL, bH, bL)
    }
    const int h = s * 16 + m16;
#pragma unroll
    for (int r = 0; r < 4; ++r) {
      int idx = SWZ6(quad * 4 + r, h);
      split2(af[r], zfH[idx], zfL[idx]);
    }
  }
  {
    float s2[4];
#pragma unroll
    for (int r = 0; r < 4; ++r)
      s2[r] = accA[0][r] * accA[0][r] + accA[1][r] * accA[1][r];
#pragma unroll
    for (int n = 0; n < 2; ++n) {
      const int h = (half * 2 + n) * 16 + m16;
#pragma unroll
      for (int r = 0; r < 4; ++r) {
        int idx = SWZ6(row0 + quad * 4 + r, h);
        split2(accA[n][r], b1H[idx], b1L[idx]);
      }
    }
#pragma unroll
    for (int m = 1; m < 16; m <<= 1)
#pragma unroll
      for (int r = 0; r < 4; ++r) s2[r] += __shfl_xor(s2[r], m);
    if (m16 == 0) {
#pragma unroll
      for (int r = 0; r < 4; ++r)
        spH2[(row0 + quad * 4 + r) * 2 + half] = s2[r];
    }
  }
  __syncthreads();   // B10

  if (t >= 64 && t < 320) {
    // sfS parallelized: 16 j x 16 lanes, 4 h each + shfl tree
    int idx = t - 64;
    int j = idx >> 4, h0 = (idx & 15) * 4;
    float p = 0.f;
#pragma unroll
    for (int r = 0; r < 4; ++r) {
      int ii = SWZ6(j, h0 + r);
      float v = bf2f(zfH[ii]) + bf2f(zfL[ii]);
      p += v * v;
    }
#pragma unroll
    for (int m = 1; m < 16; m <<= 1) p += __shfl_xor(p, m);
    if ((idx & 15) == 0) sfS[j] = p;
  }
  __syncthreads();   // B11

  // ---- GEMM6: cross = Zp @ Zf^T (4-term); half0 writes al (spS folded) ----
  {
    f32x4 ac2 = (f32x4){0.f, 0.f, 0.f, 0.f};
#pragma unroll
    for (int kb8 = 0; kb8 < 8; kb8 += 4) {
      int ach = ((quad + kb8) ^ (m16 & 7)) << 3;
      bf16x8 aH = *(const bf16x8*)(b1H + (arow << 6) + ach);
      bf16x8 aL = *(const bf16x8*)(b1L + (arow << 6) + ach);
      bf16x8 bH = *(const bf16x8*)(zfH + (m16 << 6) + ach);
      bf16x8 bL = *(const bf16x8*)(zfL + (m16 << 6) + ach);
      MFMA4(ac2, aH, aL, bH, bL)
    }
    if (half == 0) {
#pragma unroll
      for (int r = 0; r < 4; ++r) {
        int i = row0 + quad * 4 + r;
        alS[i * 17 + m16] = sc * ((spH2[i * 2] + spH2[i * 2 + 1]) + sfS[m16] - 2.f * ac2[r]);
      }
    }
  }
  __syncthreads();   // B12

  // ---- masked softmax over j per i ----
  if (t < 64) {
    const int i = t;
    float lv[16];
    float m = -3.4e38f;
#pragma unroll
    for (int j = 0; j < 16; ++j) {
      float v = (mk[j * 64 + i] != 0.f) ? alS[i * 17 + j] : NEGBIG;
      lv[j] = v;
      m = fmaxf(m, v);
    }
    float ssum = 0.f;
#pragma unroll
    for (int j = 0; j < 16; ++j) { lv[j] = expf(lv[j] - m); ssum += lv[j]; }
    float inv = 1.f / ssum;
#pragma unroll
    for (int j = 0; j < 16; ++j) alS[i * 17 + j] = lv[j] * inv;
  }
  __syncthreads();   // B13

  // yh parallelized: 16 j x 16 lanes, 4 i each + shfl tree
  if (t < 256) {
    int j = t >> 4, i0 = (t & 15) * 4;
    float p = 0.f;
#pragma unroll
    for (int r = 0; r < 4; ++r) p += alS[(i0 + r) * 17 + j] * yvS[i0 + r];
#pragma unroll
    for (int m = 1; m < 16; m <<= 1) p += __shfl_xor(p, m);
    if ((t & 15) == 0) yhsS[j] = p;
  }
  __syncthreads();   // B14

  // ---- stage xc (dist) + g2 scratch ----
  for (int e = t; e < 5120; e += 512) {
    int n = e >> 6, c = e & 63;
    float v = 0.f;
    if (c < 50)       v = xbuf[n * 51 + c];
    else if (c == 50) v = (n < 64) ? xbuf[n * 51 + 50] : yhsS[n - 64];
    int idx = SWZ6(n, c);
    split2(v, xcH[idx], xcL[idx]);
  }
  for (int e = t; e < 832; e += 512) {
    int r = e / 52, c = e - r * 52;
    float v = 0.f;
    if (c < 50)       v = xbuf[(64 + r) * 51 + c];
    else if (c == 50) v = yhsS[r];
    X2v[e] = v;
  }
  for (int e = t; e < 256; e += 512) A22v[e] = an22[e];
  if (t < 64) wb2[t] = wg2b[t];
  __syncthreads();   // B15

  // ---- dist Gram (all waves, 25 tiles over 8 waves) + sq diag ----
  f32x4 accD[4];
  {
    int tc = 0;
    for (int idx = wave; idx < 25; idx += 8) {
      int ts = idx / 5, tf = idx - ts * 5;
      f32x4 acc = (f32x4){0.f, 0.f, 0.f, 0.f};
#pragma unroll
      for (int kb8 = 0; kb8 < 8; kb8 += 4) {
        int ach = ((quad + kb8) ^ (m16 & 7)) << 3;
        bf16x8 aH = *(const bf16x8*)(xcH + ((ts * 16 + m16) << 6) + ach);
        bf16x8 aL = *(const bf16x8*)(xcL + ((ts * 16 + m16) << 6) + ach);
        const int col = tf * 16 + m16;
        int boff = (col << 6) + ach;
        bf16x8 bH = *(const bf16x8*)(xcH + boff);
        bf16x8 bL = *(const bf16x8*)(xcL + boff);
        MFMA3(acc, aH, aL, bH, bL)
      }
      if (ts == tf && (m16 >> 2) == quad) sqS[ts * 16 + m16] = acc[m16 & 3];
      accD[tc++] = acc;
    }
  }
  // ---- g2: G = X2 @ W2a^T ----
  for (int e = t; e < 1024; e += 512) {
    int j = e >> 6, h = e & 63;
    float ssum = 0.f;
    for (int k = 0; k < 51; ++k) ssum += X2v[j * 52 + k] * g2at[k * 64 + h];
    G2v[e] = ssum;
  }
  __syncthreads();   // B16 (sq + G visible)

  // ---- g2: P = relu(A22 @ G) ----
  for (int e = t; e < 1024; e += 512) {
    int j = e >> 6, h = e & 63;
    float ssum = 0.f;
#pragma unroll
    for (int k = 0; k < 16; ++k) ssum += A22v[j * 16 + k] * G2v[k * 64 + h];
    Pmv[e] = ssum > 0.f ? ssum : 0.f;
  }
  // ---- dist epilogue + stores ----
  {
    float* dist = out + OUT_DIST + b * 6400;
    int tc = 0;
    for (int idx = wave; idx < 25; idx += 8) {
      int ts = idx / 5, tf = idx - ts * 5;
      f32x4 acc = accD[tc++];
#pragma unroll
      for (int r = 0; r < 4; ++r) {
        int i = ts * 16 + quad * 4 + r;
        int m = tf * 16 + m16;
        float d2 = sqS[i] + sqS[m] - 2.f * acc[r];
        d2 = d2 > 0.f ? d2 : 0.f;
        dist[i * 80 + m] = d2 > 0.f ? sqrtf(d2) : 0.f;
      }
    }
  }
  __syncthreads();   // B17
  // zz parallelized: 16 j x 16 lanes, 4 h each + shfl tree
  if (t < 256) {
    int j = t >> 4, h0 = (t & 15) * 4;
    float p = 0.f;
#pragma unroll
    for (int r = 0; r < 4; ++r) p += Pmv[j * 64 + h0 + r] * wb2[h0 + r];
#pragma unroll
    for (int m = 1; m < 16; m <<= 1) p += __shfl_xor(p, m);
    if ((t & 15) == 0) zzv[j] = p;
  }
  __syncthreads();   // B18
  if (t < 16) {
    float ssum = 0.f;
#pragma unroll
    for (int k = 0; k < 16; ++k) ssum += A22v[t * 16 + k] * zzv[k];
    out[OUT_OUT + b * 16 + t] = ssum;
  }
}

// ===========================================================================
extern "C" void kernel_launch(void* const* d_in, const int* in_sizes, int n_in,
                              void* d_out, int out_size, void* d_ws, size_t ws_size,
                              hipStream_t stream)
{
  const float* data = (const float*)d_in[0];
  const float* emb0 = (const float*)d_in[1];
  const float* emb1 = (const float*)d_in[2];
  const float* emb2 = (const float*)d_in[3];
  const float* w1   = (const float*)d_in[4];
  const float* b1   = (const float*)d_in[5];
  const float* w2   = (const float*)d_in[6];
  const float* b2   = (const float*)d_in[7];
  const float* w3   = (const float*)d_in[8];
  const float* b3   = (const float*)d_in[9];
  const float* M    = (const float*)d_in[10];
  const float* wg1a = (const float*)d_in[11];
  const float* wg1b = (const float*)d_in[12];
  const float* Wk   = (const float*)d_in[13];
  const float* smo  = (const float*)d_in[14];
  const float* wg2a = (const float*)d_in[15];
  const float* wg2b = (const float*)d_in[16];
  float* ws  = (float*)d_ws;
  float* out = (float*)d_out;

  k_prep <<<dim3(4),    dim3(256), 0, stream>>>(M, Wk, smo, w1, w2, w3, wg1a, wg1b, wg2a, ws, out);
  k_fused<<<dim3(1024), dim3(512), 0, stream>>>(data, emb0, emb1, emb2, b1, b2, b3, wg2b, ws, out);
}